// Round 6
// baseline (1204.390 us; speedup 1.0000x reference)
//
#include <hip/hip_runtime.h>

#define NB   8
#define NPT  2048
#define KNN  20
#define CLS  40
#define EPSBN 1e-5f

typedef _Float16 f16x8 __attribute__((ext_vector_type(8)));
typedef short    short8 __attribute__((ext_vector_type(8)));
typedef float    f32x4 __attribute__((ext_vector_type(4)));

struct P {
    const float *x,*w1,*bn1,*w2,*bn2,*w3,*bn3,*w4,*bn4,*w5,*bn5,*w6,*bn6;
    const float *lw1,*lb1,*lbn1,*lw2,*lb2,*lbn2,*lw3,*lb3;
    float *xT0,*xT1,*xT2,*xT3,*h5T,*xx;
    int   *idx;                       // [4][B*N][KNN]
    float *wAT1,*wCT1,*wAT2,*wCT2,*wAT3,*wCT3,*wAT4,*wCT4;
    float *ab;                        // packed alpha/beta, see offsets below
    float *zA,*zC;                    // per-stage fp32 projections (scratch, reused)
    _Float16 *zAh,*zCh;               // fp16 projections kept per stage: [4][B*N][64]
    _Float16 *xh,*xl;                 // fp16 hi/lo split of current stage src [pt][64] (scratch)
    _Float16 *xh0,*xl0;               // stage-0 padded split [pt][32]
    _Float16 *w5h;                    // a5-prescaled W5, fp16 (64x256)
    float *w6T,*lw1T,*lw2T;
    float *pmax,*psum;
    float *out;
};
// ab offsets: a1=0 b1=64 a2=128 b2=192 a3=256 b3=320 a4=384 b4=448
//             a5=512 b5=576 a6=640(256) b6=896(256) ah1=1152(256) bh1=1408(256)
//             ah2=1664(64) bh2=1728(64)   total 1792

__device__ __forceinline__ float lrl(float v, float s){ return v >= 0.f ? v : s*v; }
__device__ __forceinline__ unsigned umn(unsigned a, unsigned b){ return a < b ? a : b; }

// packed fp16 leaky-relu(0.2) via sign-mask select
__device__ __forceinline__ f16x8 lrl8(f16x8 v){
    f16x8 t = v * (_Float16)0.2f;
    short8 m = ((short8)v) >> 15;
    short8 r = (((short8)t) & m) | (((short8)v) & ~m);
    return (f16x8)r;
}

// ---------------------------------------------------------------- prep
__global__ __launch_bounds__(256) void k_prep(P p){
    int gid = blockIdx.x*256 + threadIdx.x;
    int gsz = gridDim.x*256;
    for (int i = gid; i < NB*NPT*4; i += gsz){
        int c = i & 3; int pt = i >> 2; int n = pt & (NPT-1); int b = pt >> 11;
        p.xT0[i] = (c < 3) ? p.x[((size_t)b*3 + c)*NPT + n] : 0.f;
    }
    // stage-0 split, padded to K=32: [pt][32]
    for (int i = gid; i < NB*NPT*32; i += gsz){
        int c = i & 31; int pt = i >> 5; int n = pt & (NPT-1); int b = pt >> 11;
        float xv = (c < 3) ? p.x[((size_t)b*3 + c)*NPT + n] : 0.f;
        _Float16 h = (_Float16)xv;
        p.xh0[i] = h;
        p.xl0[i] = (_Float16)(xv - (float)h);
    }
    for (int e = gid; e < 4*64; e += gsz){
        int c = e >> 6, o = e & 63;
        float a  = (c < 3) ? p.w1[o*6 + c]     : 0.f;
        float bw = (c < 3) ? p.w1[o*6 + 3 + c] : 0.f;
        p.wAT1[e] = a; p.wCT1[e] = bw - a;
    }
    #pragma unroll
    for (int k = 0; k < 3; ++k){
        const float* wsrc = (k==0) ? p.w2 : (k==1 ? p.w3 : p.w4);
        float* wa = (k==0) ? p.wAT2 : (k==1 ? p.wAT3 : p.wAT4);
        float* wc = (k==0) ? p.wCT2 : (k==1 ? p.wCT3 : p.wCT4);
        for (int e = gid; e < 64*64; e += gsz){
            int c = e >> 6, o = e & 63;
            float a = wsrc[o*128 + c];
            wa[e] = a;
            wc[e] = wsrc[o*128 + 64 + c] - a;
        }
    }
    for (int e = gid; e < 64*256; e += gsz){
        int o = e >> 8;
        float a5 = p.bn5[o] * rsqrtf(p.bn5[3*64 + o] + EPSBN);
        p.w5h[e] = (_Float16)(a5 * p.w5[e]);
    }
    for (int e = gid; e < 64*256;  e += gsz){ int c=e>>8, o=e&255; p.w6T[e]  = p.w6[o*64+c];   }
    for (int e = gid; e < 512*256; e += gsz){ int c=e>>8, o=e&255; p.lw1T[e] = p.lw1[o*512+c]; }
    for (int e = gid; e < 256*64;  e += gsz){ int c=e>>6, o=e&63;  p.lw2T[e] = p.lw2[o*256+c]; }
    auto ab = [&](const float* bn, int C, float* A, float* Bv, const float* lb){
        for (int c = gid; c < C; c += gsz){
            float s = bn[c], bb = bn[C+c], m = bn[2*C+c], v = bn[3*C+c];
            float al = s * rsqrtf(v + EPSBN);
            float be = bb - m*al;
            if (lb) be += al*lb[c];
            A[c] = al; Bv[c] = be;
        }
    };
    ab(p.bn1, 64,  p.ab+0,    p.ab+64,   nullptr);
    ab(p.bn2, 64,  p.ab+128,  p.ab+192,  nullptr);
    ab(p.bn3, 64,  p.ab+256,  p.ab+320,  nullptr);
    ab(p.bn4, 64,  p.ab+384,  p.ab+448,  nullptr);
    ab(p.bn5, 64,  p.ab+512,  p.ab+576,  nullptr);
    ab(p.bn6, 256, p.ab+640,  p.ab+896,  nullptr);
    ab(p.lbn1,256, p.ab+1152, p.ab+1408, p.lb1);
    ab(p.lbn2,64,  p.ab+1664, p.ab+1728, p.lb2);
}

// ---------------------------------------------------------------- norms
template<int C>
__global__ __launch_bounds__(256) void k_norm(const float* __restrict__ src, float* __restrict__ xx){
    int pt = blockIdx.x*256 + threadIdx.x;
    if (pt >= NB*NPT) return;
    const float4* r = (const float4*)(src + (size_t)pt*C);
    float s = 0.f;
    #pragma unroll
    for (int i = 0; i < C/4; i++){ float4 v = r[i]; s += v.x*v.x + v.y*v.y + v.z*v.z + v.w*v.w; }
    xx[pt] = s;
}

// ---------------------------------------------------------------- fused kNN: dist (split-fp16 MFMA) + top-20 select
// block = 16 rows of one batch; LDS holds 16x2048 fp32 distances (128 KiB).
// KK=32 (stage 0, padded C=4) or KK=64 (stages 1-3).
template<int KK>
__global__ __launch_bounds__(256) void k_knn(const _Float16* __restrict__ xh, const _Float16* __restrict__ xl,
                                             const float* __restrict__ xx, int* __restrict__ idxo){
    __shared__ float Dt[16*2048];
    int w = threadIdx.x >> 6, l = threadIdx.x & 63;
    int lo = l & 15, hi = l >> 4;
    int b = blockIdx.y;
    int n0 = blockIdx.x*16;
    const _Float16* xhb = xh + (size_t)b*NPT*KK;
    const _Float16* xlb = xl + (size_t)b*NPT*KK;
    const float* xxb = xx + (size_t)b*NPT;
    constexpr int NF = KK/32;
    f16x8 ah[NF], al[NF];
    #pragma unroll
    for (int kk = 0; kk < NF; kk++){
        ah[kk] = *(const f16x8*)(xhb + (size_t)(n0+lo)*KK + kk*32 + hi*8);
        al[kk] = *(const f16x8*)(xlb + (size_t)(n0+lo)*KK + kk*32 + hi*8);
    }
    float xn[4];
    #pragma unroll
    for (int r = 0; r < 4; r++) xn[r] = xxb[n0 + hi*4 + r];
    // ---- distance sweep: wave w covers cols [w*512, w*512+512)
    #pragma unroll 2
    for (int ct = 0; ct < 32; ct++){
        int c0 = w*512 + ct*16;
        f16x8 bh[NF], bl[NF];
        #pragma unroll
        for (int kk = 0; kk < NF; kk++){
            bh[kk] = *(const f16x8*)(xhb + (size_t)(c0+lo)*KK + kk*32 + hi*8);
            bl[kk] = *(const f16x8*)(xlb + (size_t)(c0+lo)*KK + kk*32 + hi*8);
        }
        f32x4 acc = (f32x4){0.f,0.f,0.f,0.f};
        #pragma unroll
        for (int kk = 0; kk < NF; kk++) acc = __builtin_amdgcn_mfma_f32_16x16x32_f16(ah[kk], bh[kk], acc, 0, 0, 0);
        #pragma unroll
        for (int kk = 0; kk < NF; kk++) acc = __builtin_amdgcn_mfma_f32_16x16x32_f16(ah[kk], bl[kk], acc, 0, 0, 0);
        #pragma unroll
        for (int kk = 0; kk < NF; kk++) acc = __builtin_amdgcn_mfma_f32_16x16x32_f16(al[kk], bh[kk], acc, 0, 0, 0);
        float xm = xxb[c0 + lo];
        #pragma unroll
        for (int r = 0; r < 4; r++)
            Dt[(hi*4 + r)*2048 + c0 + lo] = xn[r] + xm - 2.f*acc[r];
    }
    __syncthreads();
    // ---- selection: wave w owns rows n0 + w*4 .. +3
    for (int rr = 0; rr < 4; rr++){
        int n = n0 + w*4 + rr;
        const float* Dr = Dt + (w*4 + rr)*2048;
        unsigned key[32];
        #pragma unroll
        for (int q = 0; q < 8; q++){
            float4 v = *(const float4*)(Dr + q*256 + l*4);
            float f0 = fmaxf(v.x,0.f), f1 = fmaxf(v.y,0.f), f2 = fmaxf(v.z,0.f), f3 = fmaxf(v.w,0.f);
            key[4*q+0] = (__float_as_uint(f0) & 0xFFFFFFE0u) | (unsigned)(4*q+0);
            key[4*q+1] = (__float_as_uint(f1) & 0xFFFFFFE0u) | (unsigned)(4*q+1);
            key[4*q+2] = (__float_as_uint(f2) & 0xFFFFFFE0u) | (unsigned)(4*q+2);
            key[4*q+3] = (__float_as_uint(f3) & 0xFFFFFFE0u) | (unsigned)(4*q+3);
        }
        unsigned g[4];
        #pragma unroll
        for (int G = 0; G < 4; G++){
            unsigned mn = key[8*G];
            #pragma unroll
            for (int s = 1; s < 8; s++) mn = umn(mn, key[8*G+s]);
            g[G] = mn;
        }
        int* op = idxo + ((size_t)b*NPT + n)*KNN;
        for (int it = 0; it < KNN; ++it){
            unsigned lm = umn(umn(g[0],g[1]), umn(g[2],g[3]));
            unsigned wm = lm;
            #pragma unroll
            for (int off = 32; off; off >>= 1) wm = umn(wm, (unsigned)__shfl_xor((int)wm, off));
            unsigned long long bal = __ballot(lm == wm);
            int L = __ffsll(bal) - 1;
            int slot = (int)(wm & 31u);
            if (l == 0) op[it] = ((slot>>2)<<8) + L*4 + (slot&3);
            int Gw = slot >> 3;
            bool iwin = (l == L);
            #pragma unroll
            for (int G = 0; G < 4; G++) if (G == Gw){
                unsigned mn = 0xFFFFFFFFu;
                #pragma unroll
                for (int s = 8*G; s < 8*G+8; s++){
                    unsigned kv = key[s];
                    if (iwin && s == slot) kv = 0xFFFFFFFFu;
                    key[s] = kv;
                    mn = umn(mn, kv);
                }
                g[G] = mn;
            }
        }
    }
}

// ---------------------------------------------------------------- per-stage projection (+fp16 copies, +hi/lo split)
template<int C>
__global__ __launch_bounds__(256) void k_proj(const float* __restrict__ src,
                                              const float* __restrict__ wAT, const float* __restrict__ wCT,
                                              const float* __restrict__ A, const float* __restrict__ Bv,
                                              float* __restrict__ zA, float* __restrict__ zC,
                                              _Float16* __restrict__ zAh, _Float16* __restrict__ zCh,
                                              _Float16* __restrict__ xh, _Float16* __restrict__ xl){
    int wv = blockIdx.x*4 + (threadIdx.x>>6);
    int lane = threadIdx.x & 63;
    float wa[C], wc[C];
    #pragma unroll
    for (int c = 0; c < C; c++){ wa[c] = wAT[c*64+lane]; wc[c] = wCT[c*64+lane]; }
    float al = A[lane], be = Bv[lane];
    for (int p0 = 0; p0 < 4; p0++){
        int pt = wv*4 + p0;
        const float4* xr = (const float4*)(src + (size_t)pt*C);
        float sa = 0.f, sc = 0.f;
        #pragma unroll
        for (int i = 0; i < C/4; i++){
            float4 v = xr[i];
            sa += wa[4*i]*v.x + wa[4*i+1]*v.y + wa[4*i+2]*v.z + wa[4*i+3]*v.w;
            sc += wc[4*i]*v.x + wc[4*i+1]*v.y + wc[4*i+2]*v.z + wc[4*i+3]*v.w;
        }
        float va = al*sa, vc = al*sc + be;
        zA[(size_t)pt*64 + lane] = va;
        zC[(size_t)pt*64 + lane] = vc;
        zAh[(size_t)pt*64 + lane] = (_Float16)va;
        zCh[(size_t)pt*64 + lane] = (_Float16)vc;
        if (C == 64){
            float xv = src[(size_t)pt*64 + lane];
            _Float16 h = (_Float16)xv;
            xh[(size_t)pt*64 + lane] = h;
            xl[(size_t)pt*64 + lane] = (_Float16)(xv - (float)h);
        }
    }
}

// ---------------------------------------------------------------- edge gather + maxpool (stages 1..3 only)
__global__ __launch_bounds__(256) void k_edgeg(const int* __restrict__ idxp,
                                               const float* __restrict__ zA, const float* __restrict__ zC,
                                               float* __restrict__ dst){
    int wv = blockIdx.x*4 + (threadIdx.x>>6);
    int lane = threadIdx.x & 63;
    for (int p0 = 0; p0 < 4; p0++){
        int pt = wv*4 + p0;
        int b = pt >> 11;
        float zc = zC[(size_t)pt*64 + lane];
        const int* ip = idxp + (size_t)pt*KNN;
        const float* zb = zA + ((size_t)b*NPT)*64;
        float mv = -3.4e38f;
        #pragma unroll
        for (int j = 0; j < KNN; j++){
            float v = lrl(zb[(size_t)ip[j]*64 + lane] + zc, 0.2f);
            mv = fmaxf(mv, v);
        }
        dst[(size_t)pt*64 + lane] = mv;
    }
}

// ---------------------------------------------------------------- block5: recompute y in-register, MFMA, bn5+lrelu(max)
__global__ __launch_bounds__(256) void k_block5(P p){
    __shared__ float HS[4][16*85];
    int wid = threadIdx.x >> 6, l = threadIdx.x & 63;
    int lo = l & 15, hi = l >> 4;
    int g = blockIdx.x;                       // 4096 groups of 4 points = 80 edges
    const size_t SS   = (size_t)NB*NPT*KNN;   // idx stage stride
    const size_t ZS   = (size_t)NB*NPT*64;    // zAh/zCh stage stride
    f16x8 af[8];
    #pragma unroll
    for (int kk = 0; kk < 8; kk++)
        af[kk] = *(const f16x8*)(p.w5h + (wid*16 + lo)*256 + kk*32 + hi*8);
    f32x4 acc[5];
    #pragma unroll
    for (int et = 0; et < 5; et++) acc[et] = (f32x4){0.f,0.f,0.f,0.f};
    #pragma unroll
    for (int et = 0; et < 5; et++){
        int e  = g*80 + et*16 + lo;
        int pt = e / 20;
        int b  = pt >> 11;
        #pragma unroll
        for (int s = 0; s < 4; s++){
            int m = p.idx[(size_t)s*SS + e];
            const f16x8* za = (const f16x8*)(p.zAh + (size_t)s*ZS + ((size_t)(b*NPT + m))*64 + hi*8);
            const f16x8* zc = (const f16x8*)(p.zCh + (size_t)s*ZS + (size_t)pt*64 + hi*8);
            f16x8 y0 = lrl8(za[0] + zc[0]);
            f16x8 y1 = lrl8(za[4] + zc[4]);
            acc[et] = __builtin_amdgcn_mfma_f32_16x16x32_f16(af[2*s+0], y0, acc[et], 0, 0, 0);
            acc[et] = __builtin_amdgcn_mfma_f32_16x16x32_f16(af[2*s+1], y1, acc[et], 0, 0, 0);
        }
    }
    float* Hw = HS[wid];
    #pragma unroll
    for (int et = 0; et < 5; et++){
        #pragma unroll
        for (int r = 0; r < 4; r++)
            Hw[(hi*4 + r)*85 + et*16 + lo] = acc[et][r];
    }
    float mv = -3.4e38f;
    #pragma unroll
    for (int j = 0; j < KNN; j++)
        mv = fmaxf(mv, Hw[lo*85 + hi*20 + j]);
    int o = wid*16 + lo;
    int pt = g*4 + hi;
    float b5 = p.ab[576+o];
    p.h5T[(size_t)pt*64 + o] = lrl(mv + b5, 0.2f);
}

// ---------------------------------------------------------------- block6 conv + partial pools
__global__ __launch_bounds__(256) void k_block6(P p){
    int o = threadIdx.x;
    int ch = blockIdx.x, b = blockIdx.y;
    float w6r[64];
    #pragma unroll
    for (int c = 0; c < 64; c++) w6r[c] = p.w6T[c*256 + o];
    float a6 = p.ab[640+o], b6 = p.ab[896+o];
    float mv = -3.4e38f, sm = 0.f;
    for (int n = ch*128; n < ch*128 + 128; ++n){
        const float4* h4 = (const float4*)(p.h5T + ((size_t)b*NPT + n)*64);
        float t = 0.f;
        #pragma unroll
        for (int i = 0; i < 16; i++){
            float4 v = h4[i];
            t += w6r[4*i]*v.x + w6r[4*i+1]*v.y + w6r[4*i+2]*v.z + w6r[4*i+3]*v.w;
        }
        float y = lrl(a6*t + b6, 0.2f);
        mv = fmaxf(mv, y); sm += y;
    }
    p.pmax[((size_t)b*16 + ch)*256 + o] = mv;
    p.psum[((size_t)b*16 + ch)*256 + o] = sm;
}

// ---------------------------------------------------------------- final pool + FC head
__global__ __launch_bounds__(256) void k_head(P p){
    __shared__ float g[512], z1[256], z2[64];
    int b = blockIdx.x, o = threadIdx.x;
    float mv = -3.4e38f, sm = 0.f;
    for (int ch = 0; ch < 16; ++ch){
        mv = fmaxf(mv, p.pmax[((size_t)b*16+ch)*256 + o]);
        sm += p.psum[((size_t)b*16+ch)*256 + o];
    }
    g[o] = mv; g[256+o] = sm * (1.f/NPT);
    __syncthreads();
    float t = 0.f;
    for (int c = 0; c < 512; c++) t += g[c]*p.lw1T[c*256 + o];
    z1[o] = lrl(p.ab[1152+o]*t + p.ab[1408+o], 0.01f);
    __syncthreads();
    if (o < 64){
        float t2 = 0.f;
        for (int c = 0; c < 256; c++) t2 += z1[c]*p.lw2T[c*64 + o];
        z2[o] = lrl(p.ab[1664+o]*t2 + p.ab[1728+o], 0.01f);
    }
    __syncthreads();
    if (o < CLS){
        float t3 = p.lb3[o];
        for (int c = 0; c < 64; c++) t3 += z2[c]*p.lw3[o*64 + c];
        p.out[(size_t)b*CLS + o] = t3;
    }
}

// ---------------------------------------------------------------- host
extern "C" void kernel_launch(void* const* d_in, const int* in_sizes, int n_in,
                              void* d_out, int out_size, void* d_ws, size_t ws_size,
                              hipStream_t stream){
    P p;
    p.x   = (const float*)d_in[0];
    p.w1  = (const float*)d_in[1];  p.bn1 = (const float*)d_in[2];
    p.w2  = (const float*)d_in[3];  p.bn2 = (const float*)d_in[4];
    p.w3  = (const float*)d_in[5];  p.bn3 = (const float*)d_in[6];
    p.w4  = (const float*)d_in[7];  p.bn4 = (const float*)d_in[8];
    p.w5  = (const float*)d_in[9];  p.bn5 = (const float*)d_in[10];
    p.w6  = (const float*)d_in[11]; p.bn6 = (const float*)d_in[12];
    p.lw1 = (const float*)d_in[13]; p.lb1 = (const float*)d_in[14]; p.lbn1 = (const float*)d_in[15];
    p.lw2 = (const float*)d_in[16]; p.lb2 = (const float*)d_in[17]; p.lbn2 = (const float*)d_in[18];
    p.lw3 = (const float*)d_in[19]; p.lb3 = (const float*)d_in[20];
    p.out = (float*)d_out;

    float* w = (float*)d_ws;
    size_t off = 0;
    auto alloc = [&](size_t n)->float*{ float* r = w + off; off += (n + 63) & ~(size_t)63; return r; };
    p.xT0  = alloc((size_t)NB*NPT*4);
    p.xT1  = alloc((size_t)NB*NPT*64);
    p.xT2  = alloc((size_t)NB*NPT*64);
    p.xT3  = alloc((size_t)NB*NPT*64);
    p.h5T  = alloc((size_t)NB*NPT*64);
    p.xx   = alloc((size_t)NB*NPT);
    p.idx  = (int*)alloc((size_t)4*NB*NPT*KNN);
    p.wAT1 = alloc(256);  p.wCT1 = alloc(256);
    p.wAT2 = alloc(4096); p.wCT2 = alloc(4096);
    p.wAT3 = alloc(4096); p.wCT3 = alloc(4096);
    p.wAT4 = alloc(4096); p.wCT4 = alloc(4096);
    p.ab   = alloc(1792);
    p.zA   = alloc((size_t)NB*NPT*64);
    p.zC   = alloc((size_t)NB*NPT*64);
    const size_t ZS = (size_t)NB*NPT*64;              // fp16 elements per stage
    p.zAh = (_Float16*)alloc(4*ZS/2);
    p.zCh = (_Float16*)alloc(4*ZS/2);
    p.xh  = (_Float16*)alloc(ZS/2);
    p.xl  = (_Float16*)alloc(ZS/2);
    p.xh0 = (_Float16*)alloc((size_t)NB*NPT*32/2);
    p.xl0 = (_Float16*)alloc((size_t)NB*NPT*32/2);
    p.w5h = (_Float16*)alloc(64*256/2);
    p.w6T  = alloc(16384);
    p.lw1T = alloc(131072); p.lw2T = alloc(16384);
    p.pmax = alloc((size_t)NB*16*256);
    p.psum = alloc((size_t)NB*16*256);

    k_prep<<<64, 256, 0, stream>>>(p);
    const size_t SS = (size_t)NB*NPT*KNN;
    for (int s = 0; s < 4; s++){
        const float* src = (s==0) ? p.xT0 : (s==1 ? p.xT1 : (s==2 ? p.xT2 : p.xT3));
        int* idxs = p.idx + (size_t)s*SS;
        _Float16* zAh = p.zAh + (size_t)s*ZS;
        _Float16* zCh = p.zCh + (size_t)s*ZS;
        if (s == 0) k_norm<4><<<NB*NPT/256, 256, 0, stream>>>(src, p.xx);
        else        k_norm<64><<<NB*NPT/256, 256, 0, stream>>>(src, p.xx);
        if (s == 0)      k_proj<4 ><<<NB*NPT/16, 256, 0, stream>>>(src, p.wAT1, p.wCT1, p.ab+0,   p.ab+64,  p.zA, p.zC, zAh, zCh, p.xh, p.xl);
        else if (s == 1) k_proj<64><<<NB*NPT/16, 256, 0, stream>>>(src, p.wAT2, p.wCT2, p.ab+128, p.ab+192, p.zA, p.zC, zAh, zCh, p.xh, p.xl);
        else if (s == 2) k_proj<64><<<NB*NPT/16, 256, 0, stream>>>(src, p.wAT3, p.wCT3, p.ab+256, p.ab+320, p.zA, p.zC, zAh, zCh, p.xh, p.xl);
        else             k_proj<64><<<NB*NPT/16, 256, 0, stream>>>(src, p.wAT4, p.wCT4, p.ab+384, p.ab+448, p.zA, p.zC, zAh, zCh, p.xh, p.xl);
        if (s == 0) k_knn<32><<<dim3(NPT/16, NB), 256, 0, stream>>>(p.xh0, p.xl0, p.xx, idxs);
        else        k_knn<64><<<dim3(NPT/16, NB), 256, 0, stream>>>(p.xh,  p.xl,  p.xx, idxs);
        if (s == 0)      k_edgeg<<<NB*NPT/16, 256, 0, stream>>>(idxs, p.zA, p.zC, p.xT1);
        else if (s == 1) k_edgeg<<<NB*NPT/16, 256, 0, stream>>>(idxs, p.zA, p.zC, p.xT2);
        else if (s == 2) k_edgeg<<<NB*NPT/16, 256, 0, stream>>>(idxs, p.zA, p.zC, p.xT3);
        // s==3: x4 unused -> no edgeg; only idx4 + zAh4/zCh4 needed by block5
    }
    k_block5<<<NB*NPT/4, 256, 0, stream>>>(p);
    k_block6<<<dim3(16, NB), 256, 0, stream>>>(p);
    k_head<<<NB, 256, 0, stream>>>(p);
}

// Round 7
// 814.340 us; speedup vs baseline: 1.4790x; 1.4790x over previous
//
#include <hip/hip_runtime.h>

#define NB   8
#define NPT  2048
#define KNN  20
#define CLS  40
#define EPSBN 1e-5f

typedef _Float16 f16x8 __attribute__((ext_vector_type(8)));
typedef short    short8 __attribute__((ext_vector_type(8)));
typedef float    f32x4 __attribute__((ext_vector_type(4)));

struct P {
    const float *x,*w1,*bn1,*w2,*bn2,*w3,*bn3,*w4,*bn4,*w5,*bn5,*w6,*bn6;
    const float *lw1,*lb1,*lbn1,*lw2,*lb2,*lbn2,*lw3,*lb3;
    float *xT0,*xT1,*xT2,*xT3,*h5T,*xx;
    int   *idx;                       // [4][B*N][KNN]
    float *wAT1,*wCT1,*wAT2,*wCT2,*wAT3,*wCT3,*wAT4,*wCT4;
    float *ab;                        // packed alpha/beta, see offsets below
    float *zA,*zC;                    // per-stage fp32 projections (scratch, reused)
    _Float16 *zAh,*zCh;               // fp16 projections kept per stage: [4][B*N][64]
    _Float16 *xh,*xl;                 // fp16 hi/lo split of current stage src [pt][64] (scratch)
    _Float16 *xh0,*xl0;               // stage-0 padded split [pt][32]
    _Float16 *w5h;                    // a5-prescaled W5, fp16 (64x256)
    float *w6T,*lw1T,*lw2T;
    float *pmax,*psum;
    float *out;
};
// ab offsets: a1=0 b1=64 a2=128 b2=192 a3=256 b3=320 a4=384 b4=448
//             a5=512 b5=576 a6=640(256) b6=896(256) ah1=1152(256) bh1=1408(256)
//             ah2=1664(64) bh2=1728(64)   total 1792

__device__ __forceinline__ float lrl(float v, float s){ return v >= 0.f ? v : s*v; }
__device__ __forceinline__ unsigned umn(unsigned a, unsigned b){ return a < b ? a : b; }

// packed fp16 leaky-relu(0.2) via sign-mask select
__device__ __forceinline__ f16x8 lrl8(f16x8 v){
    f16x8 t = v * (_Float16)0.2f;
    short8 m = ((short8)v) >> 15;
    short8 r = (((short8)t) & m) | (((short8)v) & ~m);
    return (f16x8)r;
}

// ---------------------------------------------------------------- prep
__global__ __launch_bounds__(256) void k_prep(P p){
    int gid = blockIdx.x*256 + threadIdx.x;
    int gsz = gridDim.x*256;
    for (int i = gid; i < NB*NPT*4; i += gsz){
        int c = i & 3; int pt = i >> 2; int n = pt & (NPT-1); int b = pt >> 11;
        p.xT0[i] = (c < 3) ? p.x[((size_t)b*3 + c)*NPT + n] : 0.f;
    }
    // stage-0 split, padded to K=32: [pt][32]
    for (int i = gid; i < NB*NPT*32; i += gsz){
        int c = i & 31; int pt = i >> 5; int n = pt & (NPT-1); int b = pt >> 11;
        float xv = (c < 3) ? p.x[((size_t)b*3 + c)*NPT + n] : 0.f;
        _Float16 h = (_Float16)xv;
        p.xh0[i] = h;
        p.xl0[i] = (_Float16)(xv - (float)h);
    }
    for (int e = gid; e < 4*64; e += gsz){
        int c = e >> 6, o = e & 63;
        float a  = (c < 3) ? p.w1[o*6 + c]     : 0.f;
        float bw = (c < 3) ? p.w1[o*6 + 3 + c] : 0.f;
        p.wAT1[e] = a; p.wCT1[e] = bw - a;
    }
    #pragma unroll
    for (int k = 0; k < 3; ++k){
        const float* wsrc = (k==0) ? p.w2 : (k==1 ? p.w3 : p.w4);
        float* wa = (k==0) ? p.wAT2 : (k==1 ? p.wAT3 : p.wAT4);
        float* wc = (k==0) ? p.wCT2 : (k==1 ? p.wCT3 : p.wCT4);
        for (int e = gid; e < 64*64; e += gsz){
            int c = e >> 6, o = e & 63;
            float a = wsrc[o*128 + c];
            wa[e] = a;
            wc[e] = wsrc[o*128 + 64 + c] - a;
        }
    }
    for (int e = gid; e < 64*256; e += gsz){
        int o = e >> 8;
        float a5 = p.bn5[o] * rsqrtf(p.bn5[3*64 + o] + EPSBN);
        p.w5h[e] = (_Float16)(a5 * p.w5[e]);
    }
    for (int e = gid; e < 64*256;  e += gsz){ int c=e>>8, o=e&255; p.w6T[e]  = p.w6[o*64+c];   }
    for (int e = gid; e < 512*256; e += gsz){ int c=e>>8, o=e&255; p.lw1T[e] = p.lw1[o*512+c]; }
    for (int e = gid; e < 256*64;  e += gsz){ int c=e>>6, o=e&63;  p.lw2T[e] = p.lw2[o*256+c]; }
    auto ab = [&](const float* bn, int C, float* A, float* Bv, const float* lb){
        for (int c = gid; c < C; c += gsz){
            float s = bn[c], bb = bn[C+c], m = bn[2*C+c], v = bn[3*C+c];
            float al = s * rsqrtf(v + EPSBN);
            float be = bb - m*al;
            if (lb) be += al*lb[c];
            A[c] = al; Bv[c] = be;
        }
    };
    ab(p.bn1, 64,  p.ab+0,    p.ab+64,   nullptr);
    ab(p.bn2, 64,  p.ab+128,  p.ab+192,  nullptr);
    ab(p.bn3, 64,  p.ab+256,  p.ab+320,  nullptr);
    ab(p.bn4, 64,  p.ab+384,  p.ab+448,  nullptr);
    ab(p.bn5, 64,  p.ab+512,  p.ab+576,  nullptr);
    ab(p.bn6, 256, p.ab+640,  p.ab+896,  nullptr);
    ab(p.lbn1,256, p.ab+1152, p.ab+1408, p.lb1);
    ab(p.lbn2,64,  p.ab+1664, p.ab+1728, p.lb2);
}

// ---------------------------------------------------------------- norms
template<int C>
__global__ __launch_bounds__(256) void k_norm(const float* __restrict__ src, float* __restrict__ xx){
    int pt = blockIdx.x*256 + threadIdx.x;
    if (pt >= NB*NPT) return;
    const float4* r = (const float4*)(src + (size_t)pt*C);
    float s = 0.f;
    #pragma unroll
    for (int i = 0; i < C/4; i++){ float4 v = r[i]; s += v.x*v.x + v.y*v.y + v.z*v.z + v.w*v.w; }
    xx[pt] = s;
}

// ---------------------------------------------------------------- fused kNN: dist (split-fp16 MFMA) + top-20 select
// block = 16 rows of one batch, 512 threads (8 waves).
// dist: wave w sweeps cols [w*256, w*256+256). select: wave w owns rows w*2..w*2+1 (interleaved for ILP).
template<int KK>
__global__ __launch_bounds__(512) void k_knn(const _Float16* __restrict__ xh, const _Float16* __restrict__ xl,
                                             const float* __restrict__ xx, int* __restrict__ idxo){
    __shared__ float Dt[16*2048];
    int w = threadIdx.x >> 6, l = threadIdx.x & 63;
    int lo = l & 15, hi = l >> 4;
    int b = blockIdx.y;
    int n0 = blockIdx.x*16;
    const _Float16* xhb = xh + (size_t)b*NPT*KK;
    const _Float16* xlb = xl + (size_t)b*NPT*KK;
    const float* xxb = xx + (size_t)b*NPT;
    constexpr int NF = KK/32;
    f16x8 ah[NF], al[NF];
    #pragma unroll
    for (int kk = 0; kk < NF; kk++){
        ah[kk] = *(const f16x8*)(xhb + (size_t)(n0+lo)*KK + kk*32 + hi*8);
        al[kk] = *(const f16x8*)(xlb + (size_t)(n0+lo)*KK + kk*32 + hi*8);
    }
    float xn[4];
    #pragma unroll
    for (int r = 0; r < 4; r++) xn[r] = xxb[n0 + hi*4 + r];
    // ---- distance sweep
    for (int ct = 0; ct < 16; ct++){
        int c0 = w*256 + ct*16;
        f16x8 bh[NF], bl[NF];
        #pragma unroll
        for (int kk = 0; kk < NF; kk++){
            bh[kk] = *(const f16x8*)(xhb + (size_t)(c0+lo)*KK + kk*32 + hi*8);
            bl[kk] = *(const f16x8*)(xlb + (size_t)(c0+lo)*KK + kk*32 + hi*8);
        }
        f32x4 acc = (f32x4){0.f,0.f,0.f,0.f};
        #pragma unroll
        for (int kk = 0; kk < NF; kk++) acc = __builtin_amdgcn_mfma_f32_16x16x32_f16(ah[kk], bh[kk], acc, 0, 0, 0);
        #pragma unroll
        for (int kk = 0; kk < NF; kk++) acc = __builtin_amdgcn_mfma_f32_16x16x32_f16(ah[kk], bl[kk], acc, 0, 0, 0);
        #pragma unroll
        for (int kk = 0; kk < NF; kk++) acc = __builtin_amdgcn_mfma_f32_16x16x32_f16(al[kk], bh[kk], acc, 0, 0, 0);
        float xm = xxb[c0 + lo];
        #pragma unroll
        for (int r = 0; r < 4; r++)
            Dt[(hi*4 + r)*2048 + c0 + lo] = xn[r] + xm - 2.f*acc[r];
    }
    __syncthreads();
    // ---- selection: 2 rows per wave, interleaved
    unsigned key[2][32];
    unsigned g[2][4];
    int* opp[2];
    #pragma unroll
    for (int rr = 0; rr < 2; rr++){
        const float* Dr = Dt + (w*2 + rr)*2048;
        #pragma unroll
        for (int q = 0; q < 8; q++){
            float4 v = *(const float4*)(Dr + q*256 + l*4);
            float f0 = fmaxf(v.x,0.f), f1 = fmaxf(v.y,0.f), f2 = fmaxf(v.z,0.f), f3 = fmaxf(v.w,0.f);
            key[rr][4*q+0] = (__float_as_uint(f0) & 0xFFFFFFE0u) | (unsigned)(4*q+0);
            key[rr][4*q+1] = (__float_as_uint(f1) & 0xFFFFFFE0u) | (unsigned)(4*q+1);
            key[rr][4*q+2] = (__float_as_uint(f2) & 0xFFFFFFE0u) | (unsigned)(4*q+2);
            key[rr][4*q+3] = (__float_as_uint(f3) & 0xFFFFFFE0u) | (unsigned)(4*q+3);
        }
        #pragma unroll
        for (int G = 0; G < 4; G++){
            unsigned mn = key[rr][8*G];
            #pragma unroll
            for (int s = 1; s < 8; s++) mn = umn(mn, key[rr][8*G+s]);
            g[rr][G] = mn;
        }
        opp[rr] = idxo + ((size_t)b*NPT + n0 + w*2 + rr)*KNN;
    }
    for (int it = 0; it < KNN; ++it){
        unsigned lm0 = umn(umn(g[0][0],g[0][1]), umn(g[0][2],g[0][3]));
        unsigned lm1 = umn(umn(g[1][0],g[1][1]), umn(g[1][2],g[1][3]));
        unsigned wm0 = lm0, wm1 = lm1;
        #pragma unroll
        for (int off = 32; off; off >>= 1){
            wm0 = umn(wm0, (unsigned)__shfl_xor((int)wm0, off));
            wm1 = umn(wm1, (unsigned)__shfl_xor((int)wm1, off));
        }
        unsigned long long bal0 = __ballot(lm0 == wm0);
        unsigned long long bal1 = __ballot(lm1 == wm1);
        unsigned wm[2] = {wm0, wm1};
        int L[2] = {__ffsll(bal0) - 1, __ffsll(bal1) - 1};
        #pragma unroll
        for (int rr = 0; rr < 2; rr++){
            int slot = (int)(wm[rr] & 31u);
            if (l == 0) opp[rr][it] = ((slot>>2)<<8) + L[rr]*4 + (slot&3);
            int Gw = slot >> 3;
            bool iwin = (l == L[rr]);
            #pragma unroll
            for (int G = 0; G < 4; G++) if (G == Gw){
                unsigned mn = 0xFFFFFFFFu;
                #pragma unroll
                for (int s = 8*G; s < 8*G+8; s++){
                    unsigned kv = key[rr][s];
                    if (iwin && s == slot) kv = 0xFFFFFFFFu;
                    key[rr][s] = kv;
                    mn = umn(mn, kv);
                }
                g[rr][G] = mn;
            }
        }
    }
}

// ---------------------------------------------------------------- per-stage projection (+fp16 copies, +hi/lo split)
template<int C>
__global__ __launch_bounds__(256) void k_proj(const float* __restrict__ src,
                                              const float* __restrict__ wAT, const float* __restrict__ wCT,
                                              const float* __restrict__ A, const float* __restrict__ Bv,
                                              float* __restrict__ zA, float* __restrict__ zC,
                                              _Float16* __restrict__ zAh, _Float16* __restrict__ zCh,
                                              _Float16* __restrict__ xh, _Float16* __restrict__ xl){
    int wv = blockIdx.x*4 + (threadIdx.x>>6);
    int lane = threadIdx.x & 63;
    float wa[C], wc[C];
    #pragma unroll
    for (int c = 0; c < C; c++){ wa[c] = wAT[c*64+lane]; wc[c] = wCT[c*64+lane]; }
    float al = A[lane], be = Bv[lane];
    for (int p0 = 0; p0 < 4; p0++){
        int pt = wv*4 + p0;
        const float4* xr = (const float4*)(src + (size_t)pt*C);
        float sa = 0.f, sc = 0.f;
        #pragma unroll
        for (int i = 0; i < C/4; i++){
            float4 v = xr[i];
            sa += wa[4*i]*v.x + wa[4*i+1]*v.y + wa[4*i+2]*v.z + wa[4*i+3]*v.w;
            sc += wc[4*i]*v.x + wc[4*i+1]*v.y + wc[4*i+2]*v.z + wc[4*i+3]*v.w;
        }
        float va = al*sa, vc = al*sc + be;
        zA[(size_t)pt*64 + lane] = va;
        zC[(size_t)pt*64 + lane] = vc;
        zAh[(size_t)pt*64 + lane] = (_Float16)va;
        zCh[(size_t)pt*64 + lane] = (_Float16)vc;
        if (C == 64){
            float xv = src[(size_t)pt*64 + lane];
            _Float16 h = (_Float16)xv;
            xh[(size_t)pt*64 + lane] = h;
            xl[(size_t)pt*64 + lane] = (_Float16)(xv - (float)h);
        }
    }
}

// ---------------------------------------------------------------- edge gather + maxpool (stages 1..3 only)
__global__ __launch_bounds__(256) void k_edgeg(const int* __restrict__ idxp,
                                               const float* __restrict__ zA, const float* __restrict__ zC,
                                               float* __restrict__ dst){
    int wv = blockIdx.x*4 + (threadIdx.x>>6);
    int lane = threadIdx.x & 63;
    for (int p0 = 0; p0 < 4; p0++){
        int pt = wv*4 + p0;
        int b = pt >> 11;
        float zc = zC[(size_t)pt*64 + lane];
        const int* ip = idxp + (size_t)pt*KNN;
        const float* zb = zA + ((size_t)b*NPT)*64;
        float mv = -3.4e38f;
        #pragma unroll
        for (int j = 0; j < KNN; j++){
            float v = lrl(zb[(size_t)ip[j]*64 + lane] + zc, 0.2f);
            mv = fmaxf(mv, v);
        }
        dst[(size_t)pt*64 + lane] = mv;
    }
}

// ---------------------------------------------------------------- block5: recompute y in-register, MFMA, bn5+lrelu(max)
__global__ __launch_bounds__(256) void k_block5(P p){
    __shared__ float HS[4][16*85];
    int wid = threadIdx.x >> 6, l = threadIdx.x & 63;
    int lo = l & 15, hi = l >> 4;
    int g = blockIdx.x;                       // 4096 groups of 4 points = 80 edges
    const size_t SS   = (size_t)NB*NPT*KNN;   // idx stage stride
    const size_t ZS   = (size_t)NB*NPT*64;    // zAh/zCh stage stride
    f16x8 af[8];
    #pragma unroll
    for (int kk = 0; kk < 8; kk++)
        af[kk] = *(const f16x8*)(p.w5h + (wid*16 + lo)*256 + kk*32 + hi*8);
    f32x4 acc[5];
    #pragma unroll
    for (int et = 0; et < 5; et++) acc[et] = (f32x4){0.f,0.f,0.f,0.f};
    #pragma unroll
    for (int et = 0; et < 5; et++){
        int e  = g*80 + et*16 + lo;
        int pt = e / 20;
        int b  = pt >> 11;
        #pragma unroll
        for (int s = 0; s < 4; s++){
            int m = p.idx[(size_t)s*SS + e];
            const f16x8* za = (const f16x8*)(p.zAh + (size_t)s*ZS + ((size_t)(b*NPT + m))*64 + hi*8);
            const f16x8* zc = (const f16x8*)(p.zCh + (size_t)s*ZS + (size_t)pt*64 + hi*8);
            f16x8 y0 = lrl8(za[0] + zc[0]);
            f16x8 y1 = lrl8(za[4] + zc[4]);
            acc[et] = __builtin_amdgcn_mfma_f32_16x16x32_f16(af[2*s+0], y0, acc[et], 0, 0, 0);
            acc[et] = __builtin_amdgcn_mfma_f32_16x16x32_f16(af[2*s+1], y1, acc[et], 0, 0, 0);
        }
    }
    float* Hw = HS[wid];
    #pragma unroll
    for (int et = 0; et < 5; et++){
        #pragma unroll
        for (int r = 0; r < 4; r++)
            Hw[(hi*4 + r)*85 + et*16 + lo] = acc[et][r];
    }
    float mv = -3.4e38f;
    #pragma unroll
    for (int j = 0; j < KNN; j++)
        mv = fmaxf(mv, Hw[lo*85 + hi*20 + j]);
    int o = wid*16 + lo;
    int pt = g*4 + hi;
    float b5 = p.ab[576+o];
    p.h5T[(size_t)pt*64 + o] = lrl(mv + b5, 0.2f);
}

// ---------------------------------------------------------------- block6 conv + partial pools
__global__ __launch_bounds__(256) void k_block6(P p){
    int o = threadIdx.x;
    int ch = blockIdx.x, b = blockIdx.y;
    float w6r[64];
    #pragma unroll
    for (int c = 0; c < 64; c++) w6r[c] = p.w6T[c*256 + o];
    float a6 = p.ab[640+o], b6 = p.ab[896+o];
    float mv = -3.4e38f, sm = 0.f;
    for (int n = ch*128; n < ch*128 + 128; ++n){
        const float4* h4 = (const float4*)(p.h5T + ((size_t)b*NPT + n)*64);
        float t = 0.f;
        #pragma unroll
        for (int i = 0; i < 16; i++){
            float4 v = h4[i];
            t += w6r[4*i]*v.x + w6r[4*i+1]*v.y + w6r[4*i+2]*v.z + w6r[4*i+3]*v.w;
        }
        float y = lrl(a6*t + b6, 0.2f);
        mv = fmaxf(mv, y); sm += y;
    }
    p.pmax[((size_t)b*16 + ch)*256 + o] = mv;
    p.psum[((size_t)b*16 + ch)*256 + o] = sm;
}

// ---------------------------------------------------------------- final pool + FC head
__global__ __launch_bounds__(256) void k_head(P p){
    __shared__ float g[512], z1[256], z2[64];
    int b = blockIdx.x, o = threadIdx.x;
    float mv = -3.4e38f, sm = 0.f;
    for (int ch = 0; ch < 16; ++ch){
        mv = fmaxf(mv, p.pmax[((size_t)b*16+ch)*256 + o]);
        sm += p.psum[((size_t)b*16+ch)*256 + o];
    }
    g[o] = mv; g[256+o] = sm * (1.f/NPT);
    __syncthreads();
    float t = 0.f;
    for (int c = 0; c < 512; c++) t += g[c]*p.lw1T[c*256 + o];
    z1[o] = lrl(p.ab[1152+o]*t + p.ab[1408+o], 0.01f);
    __syncthreads();
    if (o < 64){
        float t2 = 0.f;
        for (int c = 0; c < 256; c++) t2 += z1[c]*p.lw2T[c*64 + o];
        z2[o] = lrl(p.ab[1664+o]*t2 + p.ab[1728+o], 0.01f);
    }
    __syncthreads();
    if (o < CLS){
        float t3 = p.lb3[o];
        for (int c = 0; c < 64; c++) t3 += z2[c]*p.lw3[o*64 + c];
        p.out[(size_t)b*CLS + o] = t3;
    }
}

// ---------------------------------------------------------------- host
extern "C" void kernel_launch(void* const* d_in, const int* in_sizes, int n_in,
                              void* d_out, int out_size, void* d_ws, size_t ws_size,
                              hipStream_t stream){
    P p;
    p.x   = (const float*)d_in[0];
    p.w1  = (const float*)d_in[1];  p.bn1 = (const float*)d_in[2];
    p.w2  = (const float*)d_in[3];  p.bn2 = (const float*)d_in[4];
    p.w3  = (const float*)d_in[5];  p.bn3 = (const float*)d_in[6];
    p.w4  = (const float*)d_in[7];  p.bn4 = (const float*)d_in[8];
    p.w5  = (const float*)d_in[9];  p.bn5 = (const float*)d_in[10];
    p.w6  = (const float*)d_in[11]; p.bn6 = (const float*)d_in[12];
    p.lw1 = (const float*)d_in[13]; p.lb1 = (const float*)d_in[14]; p.lbn1 = (const float*)d_in[15];
    p.lw2 = (const float*)d_in[16]; p.lb2 = (const float*)d_in[17]; p.lbn2 = (const float*)d_in[18];
    p.lw3 = (const float*)d_in[19]; p.lb3 = (const float*)d_in[20];
    p.out = (float*)d_out;

    float* w = (float*)d_ws;
    size_t off = 0;
    auto alloc = [&](size_t n)->float*{ float* r = w + off; off += (n + 63) & ~(size_t)63; return r; };
    p.xT0  = alloc((size_t)NB*NPT*4);
    p.xT1  = alloc((size_t)NB*NPT*64);
    p.xT2  = alloc((size_t)NB*NPT*64);
    p.xT3  = alloc((size_t)NB*NPT*64);
    p.h5T  = alloc((size_t)NB*NPT*64);
    p.xx   = alloc((size_t)NB*NPT);
    p.idx  = (int*)alloc((size_t)4*NB*NPT*KNN);
    p.wAT1 = alloc(256);  p.wCT1 = alloc(256);
    p.wAT2 = alloc(4096); p.wCT2 = alloc(4096);
    p.wAT3 = alloc(4096); p.wCT3 = alloc(4096);
    p.wAT4 = alloc(4096); p.wCT4 = alloc(4096);
    p.ab   = alloc(1792);
    p.zA   = alloc((size_t)NB*NPT*64);
    p.zC   = alloc((size_t)NB*NPT*64);
    const size_t ZS = (size_t)NB*NPT*64;              // fp16 elements per stage
    p.zAh = (_Float16*)alloc(4*ZS/2);
    p.zCh = (_Float16*)alloc(4*ZS/2);
    p.xh  = (_Float16*)alloc(ZS/2);
    p.xl  = (_Float16*)alloc(ZS/2);
    p.xh0 = (_Float16*)alloc((size_t)NB*NPT*32/2);
    p.xl0 = (_Float16*)alloc((size_t)NB*NPT*32/2);
    p.w5h = (_Float16*)alloc(64*256/2);
    p.w6T  = alloc(16384);
    p.lw1T = alloc(131072); p.lw2T = alloc(16384);
    p.pmax = alloc((size_t)NB*16*256);
    p.psum = alloc((size_t)NB*16*256);

    k_prep<<<64, 256, 0, stream>>>(p);
    const size_t SS = (size_t)NB*NPT*KNN;
    for (int s = 0; s < 4; s++){
        const float* src = (s==0) ? p.xT0 : (s==1 ? p.xT1 : (s==2 ? p.xT2 : p.xT3));
        int* idxs = p.idx + (size_t)s*SS;
        _Float16* zAh = p.zAh + (size_t)s*ZS;
        _Float16* zCh = p.zCh + (size_t)s*ZS;
        if (s == 0) k_norm<4><<<NB*NPT/256, 256, 0, stream>>>(src, p.xx);
        else        k_norm<64><<<NB*NPT/256, 256, 0, stream>>>(src, p.xx);
        if (s == 0)      k_proj<4 ><<<NB*NPT/16, 256, 0, stream>>>(src, p.wAT1, p.wCT1, p.ab+0,   p.ab+64,  p.zA, p.zC, zAh, zCh, p.xh, p.xl);
        else if (s == 1) k_proj<64><<<NB*NPT/16, 256, 0, stream>>>(src, p.wAT2, p.wCT2, p.ab+128, p.ab+192, p.zA, p.zC, zAh, zCh, p.xh, p.xl);
        else if (s == 2) k_proj<64><<<NB*NPT/16, 256, 0, stream>>>(src, p.wAT3, p.wCT3, p.ab+256, p.ab+320, p.zA, p.zC, zAh, zCh, p.xh, p.xl);
        else             k_proj<64><<<NB*NPT/16, 256, 0, stream>>>(src, p.wAT4, p.wCT4, p.ab+384, p.ab+448, p.zA, p.zC, zAh, zCh, p.xh, p.xl);
        if (s == 0) k_knn<32><<<dim3(NPT/16, NB), 512, 0, stream>>>(p.xh0, p.xl0, p.xx, idxs);
        else        k_knn<64><<<dim3(NPT/16, NB), 512, 0, stream>>>(p.xh,  p.xl,  p.xx, idxs);
        if (s == 0)      k_edgeg<<<NB*NPT/16, 256, 0, stream>>>(idxs, p.zA, p.zC, p.xT1);
        else if (s == 1) k_edgeg<<<NB*NPT/16, 256, 0, stream>>>(idxs, p.zA, p.zC, p.xT2);
        else if (s == 2) k_edgeg<<<NB*NPT/16, 256, 0, stream>>>(idxs, p.zA, p.zC, p.xT3);
        // s==3: x4 unused -> no edgeg; only idx4 + zAh4/zCh4 needed by block5
    }
    k_block5<<<NB*NPT/4, 256, 0, stream>>>(p);
    k_block6<<<dim3(16, NB), 256, 0, stream>>>(p);
    k_head<<<NB, 256, 0, stream>>>(p);
}

// Round 8
// 762.696 us; speedup vs baseline: 1.5791x; 1.0677x over previous
//
#include <hip/hip_runtime.h>

#define NB   8
#define NPT  2048
#define KNN  20
#define CLS  40
#define EPSBN 1e-5f
#define DSTR 2052   // padded LDS row stride (floats): 16B-aligned, breaks write conflicts

typedef _Float16 f16x8 __attribute__((ext_vector_type(8)));
typedef short    short8 __attribute__((ext_vector_type(8)));
typedef float    f32x4 __attribute__((ext_vector_type(4)));

struct P {
    const float *x,*w1,*bn1,*w2,*bn2,*w3,*bn3,*w4,*bn4,*w5,*bn5,*w6,*bn6;
    const float *lw1,*lb1,*lbn1,*lw2,*lb2,*lbn2,*lw3,*lb3;
    float *xT0,*xT1,*xT2,*xT3,*h5T,*xx;
    int   *idx;                       // [4][B*N][KNN]
    float *wAT1,*wCT1,*wAT2,*wCT2,*wAT3,*wCT3,*wAT4,*wCT4;
    float *ab;                        // packed alpha/beta, see offsets below
    float *zA,*zC;                    // per-stage fp32 projections (scratch, reused)
    _Float16 *zAh,*zCh;               // fp16 projections kept per stage: [4][B*N][64]
    _Float16 *xh,*xl;                 // fp16 hi/lo split of current stage src [pt][64] (scratch)
    _Float16 *xh0,*xl0;               // stage-0 padded split [pt][32]
    _Float16 *w5h;                    // a5-prescaled W5, fp16 (64x256)
    float *w6T,*lw1T,*lw2T;
    float *pmax,*psum;
    float *out;
};
// ab offsets: a1=0 b1=64 a2=128 b2=192 a3=256 b3=320 a4=384 b4=448
//             a5=512 b5=576 a6=640(256) b6=896(256) ah1=1152(256) bh1=1408(256)
//             ah2=1664(64) bh2=1728(64)   total 1792

__device__ __forceinline__ float lrl(float v, float s){ return v >= 0.f ? v : s*v; }
__device__ __forceinline__ unsigned umn(unsigned a, unsigned b){ return a < b ? a : b; }

// packed fp16 leaky-relu(0.2) via sign-mask select
__device__ __forceinline__ f16x8 lrl8(f16x8 v){
    f16x8 t = v * (_Float16)0.2f;
    short8 m = ((short8)v) >> 15;
    short8 r = (((short8)t) & m) | (((short8)v) & ~m);
    return (f16x8)r;
}

// ---------------------------------------------------------------- prep
__global__ __launch_bounds__(256) void k_prep(P p){
    int gid = blockIdx.x*256 + threadIdx.x;
    int gsz = gridDim.x*256;
    for (int i = gid; i < NB*NPT*4; i += gsz){
        int c = i & 3; int pt = i >> 2; int n = pt & (NPT-1); int b = pt >> 11;
        p.xT0[i] = (c < 3) ? p.x[((size_t)b*3 + c)*NPT + n] : 0.f;
    }
    // stage-0 split, padded to K=32: [pt][32]
    for (int i = gid; i < NB*NPT*32; i += gsz){
        int c = i & 31; int pt = i >> 5; int n = pt & (NPT-1); int b = pt >> 11;
        float xv = (c < 3) ? p.x[((size_t)b*3 + c)*NPT + n] : 0.f;
        _Float16 h = (_Float16)xv;
        p.xh0[i] = h;
        p.xl0[i] = (_Float16)(xv - (float)h);
    }
    for (int e = gid; e < 4*64; e += gsz){
        int c = e >> 6, o = e & 63;
        float a  = (c < 3) ? p.w1[o*6 + c]     : 0.f;
        float bw = (c < 3) ? p.w1[o*6 + 3 + c] : 0.f;
        p.wAT1[e] = a; p.wCT1[e] = bw - a;
    }
    #pragma unroll
    for (int k = 0; k < 3; ++k){
        const float* wsrc = (k==0) ? p.w2 : (k==1 ? p.w3 : p.w4);
        float* wa = (k==0) ? p.wAT2 : (k==1 ? p.wAT3 : p.wAT4);
        float* wc = (k==0) ? p.wCT2 : (k==1 ? p.wCT3 : p.wCT4);
        for (int e = gid; e < 64*64; e += gsz){
            int c = e >> 6, o = e & 63;
            float a = wsrc[o*128 + c];
            wa[e] = a;
            wc[e] = wsrc[o*128 + 64 + c] - a;
        }
    }
    for (int e = gid; e < 64*256; e += gsz){
        int o = e >> 8;
        float a5 = p.bn5[o] * rsqrtf(p.bn5[3*64 + o] + EPSBN);
        p.w5h[e] = (_Float16)(a5 * p.w5[e]);
    }
    for (int e = gid; e < 64*256;  e += gsz){ int c=e>>8, o=e&255; p.w6T[e]  = p.w6[o*64+c];   }
    for (int e = gid; e < 512*256; e += gsz){ int c=e>>8, o=e&255; p.lw1T[e] = p.lw1[o*512+c]; }
    for (int e = gid; e < 256*64;  e += gsz){ int c=e>>6, o=e&63;  p.lw2T[e] = p.lw2[o*256+c]; }
    auto ab = [&](const float* bn, int C, float* A, float* Bv, const float* lb){
        for (int c = gid; c < C; c += gsz){
            float s = bn[c], bb = bn[C+c], m = bn[2*C+c], v = bn[3*C+c];
            float al = s * rsqrtf(v + EPSBN);
            float be = bb - m*al;
            if (lb) be += al*lb[c];
            A[c] = al; Bv[c] = be;
        }
    };
    ab(p.bn1, 64,  p.ab+0,    p.ab+64,   nullptr);
    ab(p.bn2, 64,  p.ab+128,  p.ab+192,  nullptr);
    ab(p.bn3, 64,  p.ab+256,  p.ab+320,  nullptr);
    ab(p.bn4, 64,  p.ab+384,  p.ab+448,  nullptr);
    ab(p.bn5, 64,  p.ab+512,  p.ab+576,  nullptr);
    ab(p.bn6, 256, p.ab+640,  p.ab+896,  nullptr);
    ab(p.lbn1,256, p.ab+1152, p.ab+1408, p.lb1);
    ab(p.lbn2,64,  p.ab+1664, p.ab+1728, p.lb2);
}

// ---------------------------------------------------------------- norms
template<int C>
__global__ __launch_bounds__(256) void k_norm(const float* __restrict__ src, float* __restrict__ xx){
    int pt = blockIdx.x*256 + threadIdx.x;
    if (pt >= NB*NPT) return;
    const float4* r = (const float4*)(src + (size_t)pt*C);
    float s = 0.f;
    #pragma unroll
    for (int i = 0; i < C/4; i++){ float4 v = r[i]; s += v.x*v.x + v.y*v.y + v.z*v.z + v.w*v.w; }
    xx[pt] = s;
}

// ---------------------------------------------------------------- fused kNN: dist (split-fp16 MFMA) + top-20 select
// block = 16 rows of one batch, 1024 threads (16 waves, 4/SIMD).
// dist: wave w sweeps cols [w*128, w*128+128). select: wave w owns row w.
template<int KK>
__global__ __launch_bounds__(1024) void k_knn(const _Float16* __restrict__ xh, const _Float16* __restrict__ xl,
                                              const float* __restrict__ xx, int* __restrict__ idxo){
    __shared__ float Dt[16*DSTR];
    int w = threadIdx.x >> 6, l = threadIdx.x & 63;
    int lo = l & 15, hi = l >> 4;
    int b = blockIdx.y;
    int n0 = blockIdx.x*16;
    const _Float16* xhb = xh + (size_t)b*NPT*KK;
    const _Float16* xlb = xl + (size_t)b*NPT*KK;
    const float* xxb = xx + (size_t)b*NPT;
    constexpr int NF = KK/32;
    f16x8 ah[NF], al[NF];
    #pragma unroll
    for (int kk = 0; kk < NF; kk++){
        ah[kk] = *(const f16x8*)(xhb + (size_t)(n0+lo)*KK + kk*32 + hi*8);
        al[kk] = *(const f16x8*)(xlb + (size_t)(n0+lo)*KK + kk*32 + hi*8);
    }
    float xn[4];
    #pragma unroll
    for (int r = 0; r < 4; r++) xn[r] = xxb[n0 + hi*4 + r];
    // ---- distance sweep: 8 tiles per wave
    #pragma unroll 2
    for (int ct = 0; ct < 8; ct++){
        int c0 = w*128 + ct*16;
        f16x8 bh[NF], bl[NF];
        #pragma unroll
        for (int kk = 0; kk < NF; kk++){
            bh[kk] = *(const f16x8*)(xhb + (size_t)(c0+lo)*KK + kk*32 + hi*8);
            bl[kk] = *(const f16x8*)(xlb + (size_t)(c0+lo)*KK + kk*32 + hi*8);
        }
        f32x4 acc = (f32x4){0.f,0.f,0.f,0.f};
        #pragma unroll
        for (int kk = 0; kk < NF; kk++) acc = __builtin_amdgcn_mfma_f32_16x16x32_f16(ah[kk], bh[kk], acc, 0, 0, 0);
        #pragma unroll
        for (int kk = 0; kk < NF; kk++) acc = __builtin_amdgcn_mfma_f32_16x16x32_f16(ah[kk], bl[kk], acc, 0, 0, 0);
        #pragma unroll
        for (int kk = 0; kk < NF; kk++) acc = __builtin_amdgcn_mfma_f32_16x16x32_f16(al[kk], bh[kk], acc, 0, 0, 0);
        float xm = xxb[c0 + lo];
        #pragma unroll
        for (int r = 0; r < 4; r++)
            Dt[(hi*4 + r)*DSTR + c0 + lo] = xn[r] + xm - 2.f*acc[r];
    }
    __syncthreads();
    // ---- selection: wave w owns row w
    const float* Dr = Dt + w*DSTR;
    unsigned key[32];
    #pragma unroll
    for (int q = 0; q < 8; q++){
        float4 v = *(const float4*)(Dr + q*256 + l*4);
        float f0 = fmaxf(v.x,0.f), f1 = fmaxf(v.y,0.f), f2 = fmaxf(v.z,0.f), f3 = fmaxf(v.w,0.f);
        key[4*q+0] = (__float_as_uint(f0) & 0xFFFFFFE0u) | (unsigned)(4*q+0);
        key[4*q+1] = (__float_as_uint(f1) & 0xFFFFFFE0u) | (unsigned)(4*q+1);
        key[4*q+2] = (__float_as_uint(f2) & 0xFFFFFFE0u) | (unsigned)(4*q+2);
        key[4*q+3] = (__float_as_uint(f3) & 0xFFFFFFE0u) | (unsigned)(4*q+3);
    }
    unsigned g[4];
    #pragma unroll
    for (int G = 0; G < 4; G++){
        unsigned mn = key[8*G];
        #pragma unroll
        for (int s = 1; s < 8; s++) mn = umn(mn, key[8*G+s]);
        g[G] = mn;
    }
    int* op = idxo + ((size_t)b*NPT + n0 + w)*KNN;
    for (int it = 0; it < KNN; ++it){
        unsigned lm = umn(umn(g[0],g[1]), umn(g[2],g[3]));
        unsigned wm = lm;
        #pragma unroll
        for (int off = 32; off; off >>= 1) wm = umn(wm, (unsigned)__shfl_xor((int)wm, off));
        unsigned long long bal = __ballot(lm == wm);
        int L = __ffsll(bal) - 1;
        int slot = (int)(wm & 31u);
        if (l == 0) op[it] = ((slot>>2)<<8) + L*4 + (slot&3);
        int Gw = slot >> 3;
        bool iwin = (l == L);
        #pragma unroll
        for (int G = 0; G < 4; G++) if (G == Gw){
            unsigned mn = 0xFFFFFFFFu;
            #pragma unroll
            for (int s = 8*G; s < 8*G+8; s++){
                unsigned kv = key[s];
                if (iwin && s == slot) kv = 0xFFFFFFFFu;
                key[s] = kv;
                mn = umn(mn, kv);
            }
            g[G] = mn;
        }
    }
}

// ---------------------------------------------------------------- per-stage projection (+fp16 copies, +hi/lo split)
template<int C>
__global__ __launch_bounds__(256) void k_proj(const float* __restrict__ src,
                                              const float* __restrict__ wAT, const float* __restrict__ wCT,
                                              const float* __restrict__ A, const float* __restrict__ Bv,
                                              float* __restrict__ zA, float* __restrict__ zC,
                                              _Float16* __restrict__ zAh, _Float16* __restrict__ zCh,
                                              _Float16* __restrict__ xh, _Float16* __restrict__ xl){
    int wv = blockIdx.x*4 + (threadIdx.x>>6);
    int lane = threadIdx.x & 63;
    float wa[C], wc[C];
    #pragma unroll
    for (int c = 0; c < C; c++){ wa[c] = wAT[c*64+lane]; wc[c] = wCT[c*64+lane]; }
    float al = A[lane], be = Bv[lane];
    for (int p0 = 0; p0 < 4; p0++){
        int pt = wv*4 + p0;
        const float4* xr = (const float4*)(src + (size_t)pt*C);
        float sa = 0.f, sc = 0.f;
        #pragma unroll
        for (int i = 0; i < C/4; i++){
            float4 v = xr[i];
            sa += wa[4*i]*v.x + wa[4*i+1]*v.y + wa[4*i+2]*v.z + wa[4*i+3]*v.w;
            sc += wc[4*i]*v.x + wc[4*i+1]*v.y + wc[4*i+2]*v.z + wc[4*i+3]*v.w;
        }
        float va = al*sa, vc = al*sc + be;
        zA[(size_t)pt*64 + lane] = va;
        zC[(size_t)pt*64 + lane] = vc;
        zAh[(size_t)pt*64 + lane] = (_Float16)va;
        zCh[(size_t)pt*64 + lane] = (_Float16)vc;
        if (C == 64){
            float xv = src[(size_t)pt*64 + lane];
            _Float16 h = (_Float16)xv;
            xh[(size_t)pt*64 + lane] = h;
            xl[(size_t)pt*64 + lane] = (_Float16)(xv - (float)h);
        }
    }
}

// ---------------------------------------------------------------- edge gather + maxpool (stages 1..3 only)
__global__ __launch_bounds__(256) void k_edgeg(const int* __restrict__ idxp,
                                               const float* __restrict__ zA, const float* __restrict__ zC,
                                               float* __restrict__ dst){
    int wv = blockIdx.x*4 + (threadIdx.x>>6);
    int lane = threadIdx.x & 63;
    for (int p0 = 0; p0 < 4; p0++){
        int pt = wv*4 + p0;
        int b = pt >> 11;
        float zc = zC[(size_t)pt*64 + lane];
        const int* ip = idxp + (size_t)pt*KNN;
        const float* zb = zA + ((size_t)b*NPT)*64;
        float mv = -3.4e38f;
        #pragma unroll
        for (int j = 0; j < KNN; j++){
            float v = lrl(zb[(size_t)ip[j]*64 + lane] + zc, 0.2f);
            mv = fmaxf(mv, v);
        }
        dst[(size_t)pt*64 + lane] = mv;
    }
}

// ---------------------------------------------------------------- block5: recompute y in-register, MFMA, bn5+lrelu(max)
__global__ __launch_bounds__(256) void k_block5(P p){
    __shared__ float HS[4][16*85];
    int wid = threadIdx.x >> 6, l = threadIdx.x & 63;
    int lo = l & 15, hi = l >> 4;
    int g = blockIdx.x;                       // 4096 groups of 4 points = 80 edges
    const size_t SS   = (size_t)NB*NPT*KNN;   // idx stage stride
    const size_t ZS   = (size_t)NB*NPT*64;    // zAh/zCh stage stride
    f16x8 af[8];
    #pragma unroll
    for (int kk = 0; kk < 8; kk++)
        af[kk] = *(const f16x8*)(p.w5h + (wid*16 + lo)*256 + kk*32 + hi*8);
    // prefetch all 20 neighbor indices (breaks idx->gather serial chain)
    int mm[5][4];
    #pragma unroll
    for (int et = 0; et < 5; et++){
        int e = g*80 + et*16 + lo;
        #pragma unroll
        for (int s = 0; s < 4; s++) mm[et][s] = p.idx[(size_t)s*SS + e];
    }
    f32x4 acc[5];
    #pragma unroll
    for (int et = 0; et < 5; et++) acc[et] = (f32x4){0.f,0.f,0.f,0.f};
    #pragma unroll
    for (int et = 0; et < 5; et++){
        int e  = g*80 + et*16 + lo;
        int pt = e / 20;
        int b  = pt >> 11;
        #pragma unroll
        for (int s = 0; s < 4; s++){
            int m = mm[et][s];
            const f16x8* za = (const f16x8*)(p.zAh + (size_t)s*ZS + ((size_t)(b*NPT + m))*64 + hi*8);
            const f16x8* zc = (const f16x8*)(p.zCh + (size_t)s*ZS + (size_t)pt*64 + hi*8);
            f16x8 y0 = lrl8(za[0] + zc[0]);
            f16x8 y1 = lrl8(za[4] + zc[4]);
            acc[et] = __builtin_amdgcn_mfma_f32_16x16x32_f16(af[2*s+0], y0, acc[et], 0, 0, 0);
            acc[et] = __builtin_amdgcn_mfma_f32_16x16x32_f16(af[2*s+1], y1, acc[et], 0, 0, 0);
        }
    }
    float* Hw = HS[wid];
    #pragma unroll
    for (int et = 0; et < 5; et++){
        #pragma unroll
        for (int r = 0; r < 4; r++)
            Hw[(hi*4 + r)*85 + et*16 + lo] = acc[et][r];
    }
    float mv = -3.4e38f;
    #pragma unroll
    for (int j = 0; j < KNN; j++)
        mv = fmaxf(mv, Hw[lo*85 + hi*20 + j]);
    int o = wid*16 + lo;
    int pt = g*4 + hi;
    float b5 = p.ab[576+o];
    p.h5T[(size_t)pt*64 + o] = lrl(mv + b5, 0.2f);
}

// ---------------------------------------------------------------- block6 conv + partial pools
__global__ __launch_bounds__(256) void k_block6(P p){
    int o = threadIdx.x;
    int ch = blockIdx.x, b = blockIdx.y;
    float w6r[64];
    #pragma unroll
    for (int c = 0; c < 64; c++) w6r[c] = p.w6T[c*256 + o];
    float a6 = p.ab[640+o], b6 = p.ab[896+o];
    float mv = -3.4e38f, sm = 0.f;
    for (int n = ch*128; n < ch*128 + 128; ++n){
        const float4* h4 = (const float4*)(p.h5T + ((size_t)b*NPT + n)*64);
        float t = 0.f;
        #pragma unroll
        for (int i = 0; i < 16; i++){
            float4 v = h4[i];
            t += w6r[4*i]*v.x + w6r[4*i+1]*v.y + w6r[4*i+2]*v.z + w6r[4*i+3]*v.w;
        }
        float y = lrl(a6*t + b6, 0.2f);
        mv = fmaxf(mv, y); sm += y;
    }
    p.pmax[((size_t)b*16 + ch)*256 + o] = mv;
    p.psum[((size_t)b*16 + ch)*256 + o] = sm;
}

// ---------------------------------------------------------------- final pool + FC head
__global__ __launch_bounds__(256) void k_head(P p){
    __shared__ float g[512], z1[256], z2[64];
    int b = blockIdx.x, o = threadIdx.x;
    float mv = -3.4e38f, sm = 0.f;
    for (int ch = 0; ch < 16; ++ch){
        mv = fmaxf(mv, p.pmax[((size_t)b*16+ch)*256 + o]);
        sm += p.psum[((size_t)b*16+ch)*256 + o];
    }
    g[o] = mv; g[256+o] = sm * (1.f/NPT);
    __syncthreads();
    float t = 0.f;
    for (int c = 0; c < 512; c++) t += g[c]*p.lw1T[c*256 + o];
    z1[o] = lrl(p.ab[1152+o]*t + p.ab[1408+o], 0.01f);
    __syncthreads();
    if (o < 64){
        float t2 = 0.f;
        for (int c = 0; c < 256; c++) t2 += z1[c]*p.lw2T[c*64 + o];
        z2[o] = lrl(p.ab[1664+o]*t2 + p.ab[1728+o], 0.01f);
    }
    __syncthreads();
    if (o < CLS){
        float t3 = p.lb3[o];
        for (int c = 0; c < 64; c++) t3 += z2[c]*p.lw3[o*64 + c];
        p.out[(size_t)b*CLS + o] = t3;
    }
}

// ---------------------------------------------------------------- host
extern "C" void kernel_launch(void* const* d_in, const int* in_sizes, int n_in,
                              void* d_out, int out_size, void* d_ws, size_t ws_size,
                              hipStream_t stream){
    P p;
    p.x   = (const float*)d_in[0];
    p.w1  = (const float*)d_in[1];  p.bn1 = (const float*)d_in[2];
    p.w2  = (const float*)d_in[3];  p.bn2 = (const float*)d_in[4];
    p.w3  = (const float*)d_in[5];  p.bn3 = (const float*)d_in[6];
    p.w4  = (const float*)d_in[7];  p.bn4 = (const float*)d_in[8];
    p.w5  = (const float*)d_in[9];  p.bn5 = (const float*)d_in[10];
    p.w6  = (const float*)d_in[11]; p.bn6 = (const float*)d_in[12];
    p.lw1 = (const float*)d_in[13]; p.lb1 = (const float*)d_in[14]; p.lbn1 = (const float*)d_in[15];
    p.lw2 = (const float*)d_in[16]; p.lb2 = (const float*)d_in[17]; p.lbn2 = (const float*)d_in[18];
    p.lw3 = (const float*)d_in[19]; p.lb3 = (const float*)d_in[20];
    p.out = (float*)d_out;

    float* w = (float*)d_ws;
    size_t off = 0;
    auto alloc = [&](size_t n)->float*{ float* r = w + off; off += (n + 63) & ~(size_t)63; return r; };
    p.xT0  = alloc((size_t)NB*NPT*4);
    p.xT1  = alloc((size_t)NB*NPT*64);
    p.xT2  = alloc((size_t)NB*NPT*64);
    p.xT3  = alloc((size_t)NB*NPT*64);
    p.h5T  = alloc((size_t)NB*NPT*64);
    p.xx   = alloc((size_t)NB*NPT);
    p.idx  = (int*)alloc((size_t)4*NB*NPT*KNN);
    p.wAT1 = alloc(256);  p.wCT1 = alloc(256);
    p.wAT2 = alloc(4096); p.wCT2 = alloc(4096);
    p.wAT3 = alloc(4096); p.wCT3 = alloc(4096);
    p.wAT4 = alloc(4096); p.wCT4 = alloc(4096);
    p.ab   = alloc(1792);
    p.zA   = alloc((size_t)NB*NPT*64);
    p.zC   = alloc((size_t)NB*NPT*64);
    const size_t ZS = (size_t)NB*NPT*64;              // fp16 elements per stage
    p.zAh = (_Float16*)alloc(4*ZS/2);
    p.zCh = (_Float16*)alloc(4*ZS/2);
    p.xh  = (_Float16*)alloc(ZS/2);
    p.xl  = (_Float16*)alloc(ZS/2);
    p.xh0 = (_Float16*)alloc((size_t)NB*NPT*32/2);
    p.xl0 = (_Float16*)alloc((size_t)NB*NPT*32/2);
    p.w5h = (_Float16*)alloc(64*256/2);
    p.w6T  = alloc(16384);
    p.lw1T = alloc(131072); p.lw2T = alloc(16384);
    p.pmax = alloc((size_t)NB*16*256);
    p.psum = alloc((size_t)NB*16*256);

    k_prep<<<64, 256, 0, stream>>>(p);
    const size_t SS = (size_t)NB*NPT*KNN;
    for (int s = 0; s < 4; s++){
        const float* src = (s==0) ? p.xT0 : (s==1 ? p.xT1 : (s==2 ? p.xT2 : p.xT3));
        int* idxs = p.idx + (size_t)s*SS;
        _Float16* zAh = p.zAh + (size_t)s*ZS;
        _Float16* zCh = p.zCh + (size_t)s*ZS;
        if (s == 0) k_norm<4><<<NB*NPT/256, 256, 0, stream>>>(src, p.xx);
        else        k_norm<64><<<NB*NPT/256, 256, 0, stream>>>(src, p.xx);
        if (s == 0)      k_proj<4 ><<<NB*NPT/16, 256, 0, stream>>>(src, p.wAT1, p.wCT1, p.ab+0,   p.ab+64,  p.zA, p.zC, zAh, zCh, p.xh, p.xl);
        else if (s == 1) k_proj<64><<<NB*NPT/16, 256, 0, stream>>>(src, p.wAT2, p.wCT2, p.ab+128, p.ab+192, p.zA, p.zC, zAh, zCh, p.xh, p.xl);
        else if (s == 2) k_proj<64><<<NB*NPT/16, 256, 0, stream>>>(src, p.wAT3, p.wCT3, p.ab+256, p.ab+320, p.zA, p.zC, zAh, zCh, p.xh, p.xl);
        else             k_proj<64><<<NB*NPT/16, 256, 0, stream>>>(src, p.wAT4, p.wCT4, p.ab+384, p.ab+448, p.zA, p.zC, zAh, zCh, p.xh, p.xl);
        if (s == 0) k_knn<32><<<dim3(NPT/16, NB), 1024, 0, stream>>>(p.xh0, p.xl0, p.xx, idxs);
        else        k_knn<64><<<dim3(NPT/16, NB), 1024, 0, stream>>>(p.xh,  p.xl,  p.xx, idxs);
        if (s == 0)      k_edgeg<<<NB*NPT/16, 256, 0, stream>>>(idxs, p.zA, p.zC, p.xT1);
        else if (s == 1) k_edgeg<<<NB*NPT/16, 256, 0, stream>>>(idxs, p.zA, p.zC, p.xT2);
        else if (s == 2) k_edgeg<<<NB*NPT/16, 256, 0, stream>>>(idxs, p.zA, p.zC, p.xT3);
        // s==3: x4 unused -> no edgeg; only idx4 + zAh4/zCh4 needed by block5
    }
    k_block5<<<NB*NPT/4, 256, 0, stream>>>(p);
    k_block6<<<dim3(16, NB), 256, 0, stream>>>(p);
    k_head<<<NB, 256, 0, stream>>>(p);
}

// Round 9
// 726.612 us; speedup vs baseline: 1.6575x; 1.0497x over previous
//
#include <hip/hip_runtime.h>

#define NB   8
#define NPT  2048
#define KNN  20
#define CLS  40
#define EPSBN 1e-5f
#define DSTR 2052   // padded LDS row stride (floats)

typedef _Float16 f16x8 __attribute__((ext_vector_type(8)));
typedef short    short8 __attribute__((ext_vector_type(8)));
typedef float    f32x4 __attribute__((ext_vector_type(4)));

struct P {
    const float *x,*w1,*bn1,*w2,*bn2,*w3,*bn3,*w4,*bn4,*w5,*bn5,*w6,*bn6;
    const float *lw1,*lb1,*lbn1,*lw2,*lb2,*lbn2,*lw3,*lb3;
    float *xT0,*xT1,*xT2,*xT3,*h5T,*xx;
    int   *idx;                       // [4][B*N][KNN]
    float *wAT1,*wCT1,*wAT2,*wCT2,*wAT3,*wCT3,*wAT4,*wCT4;
    float *ab;                        // packed alpha/beta, see offsets below
    float *zA,*zC;                    // per-stage fp32 projections (scratch, reused)
    _Float16 *zAh,*zCh;               // fp16 projections kept per stage: [4][B*N][64]
    _Float16 *xh,*xl;                 // fp16 hi/lo split of current stage src [pt][64] (scratch)
    _Float16 *xh0,*xl0;               // stage-0 padded split [pt][32]
    _Float16 *w5h;                    // a5-prescaled W5, fp16 (64x256)
    float *w6T,*lw1T,*lw2T;
    float *pmax,*psum;
    float *out;
};
// ab offsets: a1=0 b1=64 a2=128 b2=192 a3=256 b3=320 a4=384 b4=448
//             a5=512 b5=576 a6=640(256) b6=896(256) ah1=1152(256) bh1=1408(256)
//             ah2=1664(64) bh2=1728(64)   total 1792

__device__ __forceinline__ float lrl(float v, float s){ return v >= 0.f ? v : s*v; }
__device__ __forceinline__ unsigned umn(unsigned a, unsigned b){ return a < b ? a : b; }

// wave64 min -> SGPR via DPP prefix-min (row_shr 1/2/4/8, row_bcast15/31) + readlane(63)
__device__ __forceinline__ unsigned wave_min_sgpr(unsigned v){
    unsigned t;
    t = (unsigned)__builtin_amdgcn_update_dpp((int)v,(int)v,0x111,0xF,0xF,false); v = umn(v,t);
    t = (unsigned)__builtin_amdgcn_update_dpp((int)v,(int)v,0x112,0xF,0xF,false); v = umn(v,t);
    t = (unsigned)__builtin_amdgcn_update_dpp((int)v,(int)v,0x114,0xF,0xF,false); v = umn(v,t);
    t = (unsigned)__builtin_amdgcn_update_dpp((int)v,(int)v,0x118,0xF,0xF,false); v = umn(v,t);
    t = (unsigned)__builtin_amdgcn_update_dpp((int)v,(int)v,0x142,0xF,0xF,false); v = umn(v,t);
    t = (unsigned)__builtin_amdgcn_update_dpp((int)v,(int)v,0x143,0xF,0xF,false); v = umn(v,t);
    return (unsigned)__builtin_amdgcn_readlane((int)v, 63);
}

// packed fp16 leaky-relu(0.2) via sign-mask select
__device__ __forceinline__ f16x8 lrl8(f16x8 v){
    f16x8 t = v * (_Float16)0.2f;
    short8 m = ((short8)v) >> 15;
    short8 r = (((short8)t) & m) | (((short8)v) & ~m);
    return (f16x8)r;
}

// ---------------------------------------------------------------- prep
__global__ __launch_bounds__(256) void k_prep(P p){
    int gid = blockIdx.x*256 + threadIdx.x;
    int gsz = gridDim.x*256;
    for (int i = gid; i < NB*NPT*4; i += gsz){
        int c = i & 3; int pt = i >> 2; int n = pt & (NPT-1); int b = pt >> 11;
        p.xT0[i] = (c < 3) ? p.x[((size_t)b*3 + c)*NPT + n] : 0.f;
    }
    // stage-0 split, padded to K=32: [pt][32]
    for (int i = gid; i < NB*NPT*32; i += gsz){
        int c = i & 31; int pt = i >> 5; int n = pt & (NPT-1); int b = pt >> 11;
        float xv = (c < 3) ? p.x[((size_t)b*3 + c)*NPT + n] : 0.f;
        _Float16 h = (_Float16)xv;
        p.xh0[i] = h;
        p.xl0[i] = (_Float16)(xv - (float)h);
    }
    for (int e = gid; e < 4*64; e += gsz){
        int c = e >> 6, o = e & 63;
        float a  = (c < 3) ? p.w1[o*6 + c]     : 0.f;
        float bw = (c < 3) ? p.w1[o*6 + 3 + c] : 0.f;
        p.wAT1[e] = a; p.wCT1[e] = bw - a;
    }
    #pragma unroll
    for (int k = 0; k < 3; ++k){
        const float* wsrc = (k==0) ? p.w2 : (k==1 ? p.w3 : p.w4);
        float* wa = (k==0) ? p.wAT2 : (k==1 ? p.wAT3 : p.wAT4);
        float* wc = (k==0) ? p.wCT2 : (k==1 ? p.wCT3 : p.wCT4);
        for (int e = gid; e < 64*64; e += gsz){
            int c = e >> 6, o = e & 63;
            float a = wsrc[o*128 + c];
            wa[e] = a;
            wc[e] = wsrc[o*128 + 64 + c] - a;
        }
    }
    for (int e = gid; e < 64*256; e += gsz){
        int o = e >> 8;
        float a5 = p.bn5[o] * rsqrtf(p.bn5[3*64 + o] + EPSBN);
        p.w5h[e] = (_Float16)(a5 * p.w5[e]);
    }
    for (int e = gid; e < 64*256;  e += gsz){ int c=e>>8, o=e&255; p.w6T[e]  = p.w6[o*64+c];   }
    for (int e = gid; e < 512*256; e += gsz){ int c=e>>8, o=e&255; p.lw1T[e] = p.lw1[o*512+c]; }
    for (int e = gid; e < 256*64;  e += gsz){ int c=e>>6, o=e&63;  p.lw2T[e] = p.lw2[o*256+c]; }
    auto ab = [&](const float* bn, int C, float* A, float* Bv, const float* lb){
        for (int c = gid; c < C; c += gsz){
            float s = bn[c], bb = bn[C+c], m = bn[2*C+c], v = bn[3*C+c];
            float al = s * rsqrtf(v + EPSBN);
            float be = bb - m*al;
            if (lb) be += al*lb[c];
            A[c] = al; Bv[c] = be;
        }
    };
    ab(p.bn1, 64,  p.ab+0,    p.ab+64,   nullptr);
    ab(p.bn2, 64,  p.ab+128,  p.ab+192,  nullptr);
    ab(p.bn3, 64,  p.ab+256,  p.ab+320,  nullptr);
    ab(p.bn4, 64,  p.ab+384,  p.ab+448,  nullptr);
    ab(p.bn5, 64,  p.ab+512,  p.ab+576,  nullptr);
    ab(p.bn6, 256, p.ab+640,  p.ab+896,  nullptr);
    ab(p.lbn1,256, p.ab+1152, p.ab+1408, p.lb1);
    ab(p.lbn2,64,  p.ab+1664, p.ab+1728, p.lb2);
}

// ---------------------------------------------------------------- norms
template<int C>
__global__ __launch_bounds__(256) void k_norm(const float* __restrict__ src, float* __restrict__ xx){
    int pt = blockIdx.x*256 + threadIdx.x;
    if (pt >= NB*NPT) return;
    const float4* r = (const float4*)(src + (size_t)pt*C);
    float s = 0.f;
    #pragma unroll
    for (int i = 0; i < C/4; i++){ float4 v = r[i]; s += v.x*v.x + v.y*v.y + v.z*v.z + v.w*v.w; }
    xx[pt] = s;
}

// ---------------------------------------------------------------- fused kNN: dist (split-fp16 MFMA) + top-20 select
// block = 16 rows of one batch, 1024 threads (16 waves, 4/SIMD).
// dist: wave w sweeps cols [w*128, w*128+128). select: wave w owns row w.
template<int KK>
__global__ __launch_bounds__(1024) void k_knn(const _Float16* __restrict__ xh, const _Float16* __restrict__ xl,
                                              const float* __restrict__ xx, int* __restrict__ idxo){
    __shared__ float Dt[16*DSTR];
    int w = threadIdx.x >> 6, l = threadIdx.x & 63;
    int lo = l & 15, hi = l >> 4;
    int b = blockIdx.y;
    int n0 = blockIdx.x*16;
    const _Float16* xhb = xh + (size_t)b*NPT*KK;
    const _Float16* xlb = xl + (size_t)b*NPT*KK;
    const float* xxb = xx + (size_t)b*NPT;
    constexpr int NF = KK/32;
    f16x8 ah[NF], al[NF];
    #pragma unroll
    for (int kk = 0; kk < NF; kk++){
        ah[kk] = *(const f16x8*)(xhb + (size_t)(n0+lo)*KK + kk*32 + hi*8);
        al[kk] = *(const f16x8*)(xlb + (size_t)(n0+lo)*KK + kk*32 + hi*8);
    }
    float xn[4];
    #pragma unroll
    for (int r = 0; r < 4; r++) xn[r] = xxb[n0 + hi*4 + r];
    // ---- distance sweep: 8 tiles per wave
    #pragma unroll 2
    for (int ct = 0; ct < 8; ct++){
        int c0 = w*128 + ct*16;
        f16x8 bh[NF], bl[NF];
        #pragma unroll
        for (int kk = 0; kk < NF; kk++){
            bh[kk] = *(const f16x8*)(xhb + (size_t)(c0+lo)*KK + kk*32 + hi*8);
            bl[kk] = *(const f16x8*)(xlb + (size_t)(c0+lo)*KK + kk*32 + hi*8);
        }
        f32x4 acc = (f32x4){0.f,0.f,0.f,0.f};
        #pragma unroll
        for (int kk = 0; kk < NF; kk++) acc = __builtin_amdgcn_mfma_f32_16x16x32_f16(ah[kk], bh[kk], acc, 0, 0, 0);
        #pragma unroll
        for (int kk = 0; kk < NF; kk++) acc = __builtin_amdgcn_mfma_f32_16x16x32_f16(ah[kk], bl[kk], acc, 0, 0, 0);
        #pragma unroll
        for (int kk = 0; kk < NF; kk++) acc = __builtin_amdgcn_mfma_f32_16x16x32_f16(al[kk], bh[kk], acc, 0, 0, 0);
        float xm = xxb[c0 + lo];
        #pragma unroll
        for (int r = 0; r < 4; r++)
            Dt[(hi*4 + r)*DSTR + c0 + lo] = xn[r] + xm - 2.f*acc[r];
    }
    __syncthreads();
    // ---- selection: wave w owns row w
    const float* Dr = Dt + w*DSTR;
    unsigned key[32];
    #pragma unroll
    for (int q = 0; q < 8; q++){
        float4 v = *(const float4*)(Dr + q*256 + l*4);
        float f0 = fmaxf(v.x,0.f), f1 = fmaxf(v.y,0.f), f2 = fmaxf(v.z,0.f), f3 = fmaxf(v.w,0.f);
        key[4*q+0] = (__float_as_uint(f0) & 0xFFFFFFE0u) | (unsigned)(4*q+0);
        key[4*q+1] = (__float_as_uint(f1) & 0xFFFFFFE0u) | (unsigned)(4*q+1);
        key[4*q+2] = (__float_as_uint(f2) & 0xFFFFFFE0u) | (unsigned)(4*q+2);
        key[4*q+3] = (__float_as_uint(f3) & 0xFFFFFFE0u) | (unsigned)(4*q+3);
    }
    unsigned g[4];
    #pragma unroll
    for (int G = 0; G < 4; G++){
        unsigned mn = key[8*G];
        #pragma unroll
        for (int s = 1; s < 8; s++) mn = umn(mn, key[8*G+s]);
        g[G] = mn;
    }
    int* op = idxo + ((size_t)b*NPT + n0 + w)*KNN;
    for (int it = 0; it < KNN; ++it){
        unsigned lm = umn(umn(g[0],g[1]), umn(g[2],g[3]));
        unsigned wm = wave_min_sgpr(lm);          // SGPR: scalar slot/Gw below
        unsigned long long bal = __ballot(lm == wm);
        int L = __ffsll(bal) - 1;
        int slot = (int)(wm & 31u);
        if (l == 0) op[it] = ((slot>>2)<<8) + L*4 + (slot&3);
        int Gw = slot >> 3;
        bool iwin = (l == L);
        #pragma unroll
        for (int G = 0; G < 4; G++) if (G == Gw){   // scalar branch: one group only
            unsigned mn = 0xFFFFFFFFu;
            #pragma unroll
            for (int s = 8*G; s < 8*G+8; s++){
                unsigned kv = key[s];
                if (iwin && s == slot) kv = 0xFFFFFFFFu;
                key[s] = kv;
                mn = umn(mn, kv);
            }
            g[G] = mn;
        }
    }
}

// ---------------------------------------------------------------- per-stage projection (+fp16 copies, +hi/lo split)
template<int C>
__global__ __launch_bounds__(256) void k_proj(const float* __restrict__ src,
                                              const float* __restrict__ wAT, const float* __restrict__ wCT,
                                              const float* __restrict__ A, const float* __restrict__ Bv,
                                              float* __restrict__ zA, float* __restrict__ zC,
                                              _Float16* __restrict__ zAh, _Float16* __restrict__ zCh,
                                              _Float16* __restrict__ xh, _Float16* __restrict__ xl){
    int wv = blockIdx.x*4 + (threadIdx.x>>6);
    int lane = threadIdx.x & 63;
    float wa[C], wc[C];
    #pragma unroll
    for (int c = 0; c < C; c++){ wa[c] = wAT[c*64+lane]; wc[c] = wCT[c*64+lane]; }
    float al = A[lane], be = Bv[lane];
    for (int p0 = 0; p0 < 4; p0++){
        int pt = wv*4 + p0;
        const float4* xr = (const float4*)(src + (size_t)pt*C);
        float sa = 0.f, sc = 0.f;
        #pragma unroll
        for (int i = 0; i < C/4; i++){
            float4 v = xr[i];
            sa += wa[4*i]*v.x + wa[4*i+1]*v.y + wa[4*i+2]*v.z + wa[4*i+3]*v.w;
            sc += wc[4*i]*v.x + wc[4*i+1]*v.y + wc[4*i+2]*v.z + wc[4*i+3]*v.w;
        }
        float va = al*sa, vc = al*sc + be;
        zA[(size_t)pt*64 + lane] = va;
        zC[(size_t)pt*64 + lane] = vc;
        zAh[(size_t)pt*64 + lane] = (_Float16)va;
        zCh[(size_t)pt*64 + lane] = (_Float16)vc;
        if (C == 64){
            float xv = src[(size_t)pt*64 + lane];
            _Float16 h = (_Float16)xv;
            xh[(size_t)pt*64 + lane] = h;
            xl[(size_t)pt*64 + lane] = (_Float16)(xv - (float)h);
        }
    }
}

// ---------------------------------------------------------------- edge gather + maxpool (stages 1..3 only)
__global__ __launch_bounds__(256) void k_edgeg(const int* __restrict__ idxp,
                                               const float* __restrict__ zA, const float* __restrict__ zC,
                                               float* __restrict__ dst){
    int wv = blockIdx.x*4 + (threadIdx.x>>6);
    int lane = threadIdx.x & 63;
    for (int p0 = 0; p0 < 4; p0++){
        int pt = wv*4 + p0;
        int b = pt >> 11;
        float zc = zC[(size_t)pt*64 + lane];
        const int* ip = idxp + (size_t)pt*KNN;
        const float* zb = zA + ((size_t)b*NPT)*64;
        float mv = -3.4e38f;
        #pragma unroll
        for (int j = 0; j < KNN; j++){
            float v = lrl(zb[(size_t)ip[j]*64 + lane] + zc, 0.2f);
            mv = fmaxf(mv, v);
        }
        dst[(size_t)pt*64 + lane] = mv;
    }
}

// ---------------------------------------------------------------- block5: recompute y in-register, MFMA, bn5+lrelu(max)
__global__ __launch_bounds__(256) void k_block5(P p){
    __shared__ float HS[4][16*85];
    int wid = threadIdx.x >> 6, l = threadIdx.x & 63;
    int lo = l & 15, hi = l >> 4;
    int g = blockIdx.x;                       // 4096 groups of 4 points = 80 edges
    const size_t SS   = (size_t)NB*NPT*KNN;   // idx stage stride
    const size_t ZS   = (size_t)NB*NPT*64;    // zAh/zCh stage stride
    f16x8 af[8];
    #pragma unroll
    for (int kk = 0; kk < 8; kk++)
        af[kk] = *(const f16x8*)(p.w5h + (wid*16 + lo)*256 + kk*32 + hi*8);
    // prefetch all 20 neighbor indices (breaks idx->gather serial chain)
    int mm[5][4];
    #pragma unroll
    for (int et = 0; et < 5; et++){
        int e = g*80 + et*16 + lo;
        #pragma unroll
        for (int s = 0; s < 4; s++) mm[et][s] = p.idx[(size_t)s*SS + e];
    }
    f32x4 acc[5];
    #pragma unroll
    for (int et = 0; et < 5; et++) acc[et] = (f32x4){0.f,0.f,0.f,0.f};
    #pragma unroll
    for (int et = 0; et < 5; et++){
        int e  = g*80 + et*16 + lo;
        int pt = e / 20;
        int b  = pt >> 11;
        #pragma unroll
        for (int s = 0; s < 4; s++){
            int m = mm[et][s];
            const f16x8* za = (const f16x8*)(p.zAh + (size_t)s*ZS + ((size_t)(b*NPT + m))*64 + hi*8);
            const f16x8* zc = (const f16x8*)(p.zCh + (size_t)s*ZS + (size_t)pt*64 + hi*8);
            f16x8 y0 = lrl8(za[0] + zc[0]);
            f16x8 y1 = lrl8(za[4] + zc[4]);
            acc[et] = __builtin_amdgcn_mfma_f32_16x16x32_f16(af[2*s+0], y0, acc[et], 0, 0, 0);
            acc[et] = __builtin_amdgcn_mfma_f32_16x16x32_f16(af[2*s+1], y1, acc[et], 0, 0, 0);
        }
    }
    float* Hw = HS[wid];
    #pragma unroll
    for (int et = 0; et < 5; et++){
        #pragma unroll
        for (int r = 0; r < 4; r++)
            Hw[(hi*4 + r)*85 + et*16 + lo] = acc[et][r];
    }
    float mv = -3.4e38f;
    #pragma unroll
    for (int j = 0; j < KNN; j++)
        mv = fmaxf(mv, Hw[lo*85 + hi*20 + j]);
    int o = wid*16 + lo;
    int pt = g*4 + hi;
    float b5 = p.ab[576+o];
    p.h5T[(size_t)pt*64 + o] = lrl(mv + b5, 0.2f);
}

// ---------------------------------------------------------------- block6 conv + partial pools
__global__ __launch_bounds__(256) void k_block6(P p){
    int o = threadIdx.x;
    int ch = blockIdx.x, b = blockIdx.y;
    float w6r[64];
    #pragma unroll
    for (int c = 0; c < 64; c++) w6r[c] = p.w6T[c*256 + o];
    float a6 = p.ab[640+o], b6 = p.ab[896+o];
    float mv = -3.4e38f, sm = 0.f;
    for (int n = ch*128; n < ch*128 + 128; ++n){
        const float4* h4 = (const float4*)(p.h5T + ((size_t)b*NPT + n)*64);
        float t = 0.f;
        #pragma unroll
        for (int i = 0; i < 16; i++){
            float4 v = h4[i];
            t += w6r[4*i]*v.x + w6r[4*i+1]*v.y + w6r[4*i+2]*v.z + w6r[4*i+3]*v.w;
        }
        float y = lrl(a6*t + b6, 0.2f);
        mv = fmaxf(mv, y); sm += y;
    }
    p.pmax[((size_t)b*16 + ch)*256 + o] = mv;
    p.psum[((size_t)b*16 + ch)*256 + o] = sm;
}

// ---------------------------------------------------------------- final pool + FC head
__global__ __launch_bounds__(256) void k_head(P p){
    __shared__ float g[512], z1[256], z2[64];
    int b = blockIdx.x, o = threadIdx.x;
    float mv = -3.4e38f, sm = 0.f;
    for (int ch = 0; ch < 16; ++ch){
        mv = fmaxf(mv, p.pmax[((size_t)b*16+ch)*256 + o]);
        sm += p.psum[((size_t)b*16+ch)*256 + o];
    }
    g[o] = mv; g[256+o] = sm * (1.f/NPT);
    __syncthreads();
    float t = 0.f;
    for (int c = 0; c < 512; c++) t += g[c]*p.lw1T[c*256 + o];
    z1[o] = lrl(p.ab[1152+o]*t + p.ab[1408+o], 0.01f);
    __syncthreads();
    if (o < 64){
        float t2 = 0.f;
        for (int c = 0; c < 256; c++) t2 += z1[c]*p.lw2T[c*64 + o];
        z2[o] = lrl(p.ab[1664+o]*t2 + p.ab[1728+o], 0.01f);
    }
    __syncthreads();
    if (o < CLS){
        float t3 = p.lb3[o];
        for (int c = 0; c < 64; c++) t3 += z2[c]*p.lw3[o*64 + c];
        p.out[(size_t)b*CLS + o] = t3;
    }
}

// ---------------------------------------------------------------- host
extern "C" void kernel_launch(void* const* d_in, const int* in_sizes, int n_in,
                              void* d_out, int out_size, void* d_ws, size_t ws_size,
                              hipStream_t stream){
    P p;
    p.x   = (const float*)d_in[0];
    p.w1  = (const float*)d_in[1];  p.bn1 = (const float*)d_in[2];
    p.w2  = (const float*)d_in[3];  p.bn2 = (const float*)d_in[4];
    p.w3  = (const float*)d_in[5];  p.bn3 = (const float*)d_in[6];
    p.w4  = (const float*)d_in[7];  p.bn4 = (const float*)d_in[8];
    p.w5  = (const float*)d_in[9];  p.bn5 = (const float*)d_in[10];
    p.w6  = (const float*)d_in[11]; p.bn6 = (const float*)d_in[12];
    p.lw1 = (const float*)d_in[13]; p.lb1 = (const float*)d_in[14]; p.lbn1 = (const float*)d_in[15];
    p.lw2 = (const float*)d_in[16]; p.lb2 = (const float*)d_in[17]; p.lbn2 = (const float*)d_in[18];
    p.lw3 = (const float*)d_in[19]; p.lb3 = (const float*)d_in[20];
    p.out = (float*)d_out;

    float* w = (float*)d_ws;
    size_t off = 0;
    auto alloc = [&](size_t n)->float*{ float* r = w + off; off += (n + 63) & ~(size_t)63; return r; };
    p.xT0  = alloc((size_t)NB*NPT*4);
    p.xT1  = alloc((size_t)NB*NPT*64);
    p.xT2  = alloc((size_t)NB*NPT*64);
    p.xT3  = alloc((size_t)NB*NPT*64);
    p.h5T  = alloc((size_t)NB*NPT*64);
    p.xx   = alloc((size_t)NB*NPT);
    p.idx  = (int*)alloc((size_t)4*NB*NPT*KNN);
    p.wAT1 = alloc(256);  p.wCT1 = alloc(256);
    p.wAT2 = alloc(4096); p.wCT2 = alloc(4096);
    p.wAT3 = alloc(4096); p.wCT3 = alloc(4096);
    p.wAT4 = alloc(4096); p.wCT4 = alloc(4096);
    p.ab   = alloc(1792);
    p.zA   = alloc((size_t)NB*NPT*64);
    p.zC   = alloc((size_t)NB*NPT*64);
    const size_t ZS = (size_t)NB*NPT*64;              // fp16 elements per stage
    p.zAh = (_Float16*)alloc(4*ZS/2);
    p.zCh = (_Float16*)alloc(4*ZS/2);
    p.xh  = (_Float16*)alloc(ZS/2);
    p.xl  = (_Float16*)alloc(ZS/2);
    p.xh0 = (_Float16*)alloc((size_t)NB*NPT*32/2);
    p.xl0 = (_Float16*)alloc((size_t)NB*NPT*32/2);
    p.w5h = (_Float16*)alloc(64*256/2);
    p.w6T  = alloc(16384);
    p.lw1T = alloc(131072); p.lw2T = alloc(16384);
    p.pmax = alloc((size_t)NB*16*256);
    p.psum = alloc((size_t)NB*16*256);

    k_prep<<<64, 256, 0, stream>>>(p);
    const size_t SS = (size_t)NB*NPT*KNN;
    for (int s = 0; s < 4; s++){
        const float* src = (s==0) ? p.xT0 : (s==1 ? p.xT1 : (s==2 ? p.xT2 : p.xT3));
        int* idxs = p.idx + (size_t)s*SS;
        _Float16* zAh = p.zAh + (size_t)s*ZS;
        _Float16* zCh = p.zCh + (size_t)s*ZS;
        if (s == 0) k_norm<4><<<NB*NPT/256, 256, 0, stream>>>(src, p.xx);
        else        k_norm<64><<<NB*NPT/256, 256, 0, stream>>>(src, p.xx);
        if (s == 0)      k_proj<4 ><<<NB*NPT/16, 256, 0, stream>>>(src, p.wAT1, p.wCT1, p.ab+0,   p.ab+64,  p.zA, p.zC, zAh, zCh, p.xh, p.xl);
        else if (s == 1) k_proj<64><<<NB*NPT/16, 256, 0, stream>>>(src, p.wAT2, p.wCT2, p.ab+128, p.ab+192, p.zA, p.zC, zAh, zCh, p.xh, p.xl);
        else if (s == 2) k_proj<64><<<NB*NPT/16, 256, 0, stream>>>(src, p.wAT3, p.wCT3, p.ab+256, p.ab+320, p.zA, p.zC, zAh, zCh, p.xh, p.xl);
        else             k_proj<64><<<NB*NPT/16, 256, 0, stream>>>(src, p.wAT4, p.wCT4, p.ab+384, p.ab+448, p.zA, p.zC, zAh, zCh, p.xh, p.xl);
        if (s == 0) k_knn<32><<<dim3(NPT/16, NB), 1024, 0, stream>>>(p.xh0, p.xl0, p.xx, idxs);
        else        k_knn<64><<<dim3(NPT/16, NB), 1024, 0, stream>>>(p.xh,  p.xl,  p.xx, idxs);
        if (s == 0)      k_edgeg<<<NB*NPT/16, 256, 0, stream>>>(idxs, p.zA, p.zC, p.xT1);
        else if (s == 1) k_edgeg<<<NB*NPT/16, 256, 0, stream>>>(idxs, p.zA, p.zC, p.xT2);
        else if (s == 2) k_edgeg<<<NB*NPT/16, 256, 0, stream>>>(idxs, p.zA, p.zC, p.xT3);
        // s==3: x4 unused -> no edgeg; only idx4 + zAh4/zCh4 needed by block5
    }
    k_block5<<<NB*NPT/4, 256, 0, stream>>>(p);
    k_block6<<<dim3(16, NB), 256, 0, stream>>>(p);
    k_head<<<NB, 256, 0, stream>>>(p);
}

// Round 10
// 700.710 us; speedup vs baseline: 1.7188x; 1.0370x over previous
//
#include <hip/hip_runtime.h>

#define NB   8
#define NPT  2048
#define KNN  20
#define CLS  40
#define EPSBN 1e-5f
#define DHALF 1028   // padded LDS row stride for half-width D tile (floats)

typedef _Float16 f16x8 __attribute__((ext_vector_type(8)));
typedef _Float16 f16x4 __attribute__((ext_vector_type(4)));
typedef short    short8 __attribute__((ext_vector_type(8)));
typedef float    f32x4 __attribute__((ext_vector_type(4)));

struct P {
    const float *x,*w1,*bn1,*w2,*bn2,*w3,*bn3,*w4,*bn4,*w5,*bn5,*w6,*bn6;
    const float *lw1,*lb1,*lbn1,*lw2,*lb2,*lbn2,*lw3,*lb3;
    float *xT0,*xT1,*xT2,*xT3,*h5T,*xx;
    int   *idx;                       // [4][B*N][KNN]
    float *wAT1,*wCT1,*wAT2,*wCT2,*wAT3,*wCT3,*wAT4,*wCT4;
    float *ab;                        // packed alpha/beta, see offsets below
    float *zA,*zC;                    // per-stage fp32 projections (scratch, reused)
    _Float16 *zAh,*zCh;               // fp16 projections kept per stage: [4][B*N][64]
    _Float16 *xh,*xl;                 // fp16 hi/lo split of current stage src [pt][64] (scratch)
    _Float16 *xh0,*xl0;               // stage-0 padded split [pt][32]
    _Float16 *w5h;                    // a5-prescaled W5, fp16 (64x256)
    float *w6T,*lw1T,*lw2T;
    float *pmax,*psum;
    float *out;
};
// ab offsets: a1=0 b1=64 a2=128 b2=192 a3=256 b3=320 a4=384 b4=448
//             a5=512 b5=576 a6=640(256) b6=896(256) ah1=1152(256) bh1=1408(256)
//             ah2=1664(64) bh2=1728(64)   total 1792

__device__ __forceinline__ float lrl(float v, float s){ return v >= 0.f ? v : s*v; }
__device__ __forceinline__ unsigned umn(unsigned a, unsigned b){ return a < b ? a : b; }

// wave64 min -> SGPR via DPP prefix-min (row_shr 1/2/4/8, row_bcast15/31) + readlane(63)
__device__ __forceinline__ unsigned wave_min_sgpr(unsigned v){
    unsigned t;
    t = (unsigned)__builtin_amdgcn_update_dpp((int)v,(int)v,0x111,0xF,0xF,false); v = umn(v,t);
    t = (unsigned)__builtin_amdgcn_update_dpp((int)v,(int)v,0x112,0xF,0xF,false); v = umn(v,t);
    t = (unsigned)__builtin_amdgcn_update_dpp((int)v,(int)v,0x114,0xF,0xF,false); v = umn(v,t);
    t = (unsigned)__builtin_amdgcn_update_dpp((int)v,(int)v,0x118,0xF,0xF,false); v = umn(v,t);
    t = (unsigned)__builtin_amdgcn_update_dpp((int)v,(int)v,0x142,0xF,0xF,false); v = umn(v,t);
    t = (unsigned)__builtin_amdgcn_update_dpp((int)v,(int)v,0x143,0xF,0xF,false); v = umn(v,t);
    return (unsigned)__builtin_amdgcn_readlane((int)v, 63);
}

// packed fp16 leaky-relu(0.2) via sign-mask select
__device__ __forceinline__ f16x8 lrl8(f16x8 v){
    f16x8 t = v * (_Float16)0.2f;
    short8 m = ((short8)v) >> 15;
    short8 r = (((short8)t) & m) | (((short8)v) & ~m);
    return (f16x8)r;
}

// ---------------------------------------------------------------- prep
__global__ __launch_bounds__(256) void k_prep(P p){
    int gid = blockIdx.x*256 + threadIdx.x;
    int gsz = gridDim.x*256;
    for (int i = gid; i < NB*NPT*4; i += gsz){
        int c = i & 3; int pt = i >> 2; int n = pt & (NPT-1); int b = pt >> 11;
        p.xT0[i] = (c < 3) ? p.x[((size_t)b*3 + c)*NPT + n] : 0.f;
    }
    // stage-0 split, padded to K=32: [pt][32]
    for (int i = gid; i < NB*NPT*32; i += gsz){
        int c = i & 31; int pt = i >> 5; int n = pt & (NPT-1); int b = pt >> 11;
        float xv = (c < 3) ? p.x[((size_t)b*3 + c)*NPT + n] : 0.f;
        _Float16 h = (_Float16)xv;
        p.xh0[i] = h;
        p.xl0[i] = (_Float16)(xv - (float)h);
    }
    for (int e = gid; e < 4*64; e += gsz){
        int c = e >> 6, o = e & 63;
        float a  = (c < 3) ? p.w1[o*6 + c]     : 0.f;
        float bw = (c < 3) ? p.w1[o*6 + 3 + c] : 0.f;
        p.wAT1[e] = a; p.wCT1[e] = bw - a;
    }
    #pragma unroll
    for (int k = 0; k < 3; ++k){
        const float* wsrc = (k==0) ? p.w2 : (k==1 ? p.w3 : p.w4);
        float* wa = (k==0) ? p.wAT2 : (k==1 ? p.wAT3 : p.wAT4);
        float* wc = (k==0) ? p.wCT2 : (k==1 ? p.wCT3 : p.wCT4);
        for (int e = gid; e < 64*64; e += gsz){
            int c = e >> 6, o = e & 63;
            float a = wsrc[o*128 + c];
            wa[e] = a;
            wc[e] = wsrc[o*128 + 64 + c] - a;
        }
    }
    for (int e = gid; e < 64*256; e += gsz){
        int o = e >> 8;
        float a5 = p.bn5[o] * rsqrtf(p.bn5[3*64 + o] + EPSBN);
        p.w5h[e] = (_Float16)(a5 * p.w5[e]);
    }
    for (int e = gid; e < 64*256;  e += gsz){ int c=e>>8, o=e&255; p.w6T[e]  = p.w6[o*64+c];   }
    for (int e = gid; e < 512*256; e += gsz){ int c=e>>8, o=e&255; p.lw1T[e] = p.lw1[o*512+c]; }
    for (int e = gid; e < 256*64;  e += gsz){ int c=e>>6, o=e&63;  p.lw2T[e] = p.lw2[o*256+c]; }
    auto ab = [&](const float* bn, int C, float* A, float* Bv, const float* lb){
        for (int c = gid; c < C; c += gsz){
            float s = bn[c], bb = bn[C+c], m = bn[2*C+c], v = bn[3*C+c];
            float al = s * rsqrtf(v + EPSBN);
            float be = bb - m*al;
            if (lb) be += al*lb[c];
            A[c] = al; Bv[c] = be;
        }
    };
    ab(p.bn1, 64,  p.ab+0,    p.ab+64,   nullptr);
    ab(p.bn2, 64,  p.ab+128,  p.ab+192,  nullptr);
    ab(p.bn3, 64,  p.ab+256,  p.ab+320,  nullptr);
    ab(p.bn4, 64,  p.ab+384,  p.ab+448,  nullptr);
    ab(p.bn5, 64,  p.ab+512,  p.ab+576,  nullptr);
    ab(p.bn6, 256, p.ab+640,  p.ab+896,  nullptr);
    ab(p.lbn1,256, p.ab+1152, p.ab+1408, p.lb1);
    ab(p.lbn2,64,  p.ab+1664, p.ab+1728, p.lb2);
}

// ---------------------------------------------------------------- fused kNN: two-half dist (split-fp16 MFMA) + top-20
// block = 16 rows of one batch, 1024 threads (16 waves). LDS holds a 16x1024 half-tile (65.8 KB) -> 2 blocks/CU.
// XCD pinning: batch = blockIdx.x & 7 (round-robin XCD assignment keeps each XCD on one batch slice).
template<int KK>
__global__ __launch_bounds__(1024, 8) void k_knn(const _Float16* __restrict__ xh, const _Float16* __restrict__ xl,
                                                 const float* __restrict__ xx, int* __restrict__ idxo){
    __shared__ float Dt[16*DHALF];
    int w = threadIdx.x >> 6, l = threadIdx.x & 63;
    int lo = l & 15, hi = l >> 4;
    int id = blockIdx.x;
    int b = id & 7;
    int n0 = (id >> 3) * 16;
    const _Float16* xhb = xh + (size_t)b*NPT*KK;
    const _Float16* xlb = xl + (size_t)b*NPT*KK;
    const float* xxb = xx + (size_t)b*NPT;
    constexpr int NF = KK/32;
    f16x8 ah[NF], al[NF];
    #pragma unroll
    for (int kk = 0; kk < NF; kk++){
        ah[kk] = *(const f16x8*)(xhb + (size_t)(n0+lo)*KK + kk*32 + hi*8);
        al[kk] = *(const f16x8*)(xlb + (size_t)(n0+lo)*KK + kk*32 + hi*8);
    }
    float xn[4];
    #pragma unroll
    for (int r = 0; r < 4; r++) xn[r] = xxb[n0 + hi*4 + r];
    unsigned key[32];
    #pragma unroll
    for (int half = 0; half < 2; half++){
        // ---- dist: wave w covers local cols [w*64, w*64+64) of this half
        #pragma unroll
        for (int ct = 0; ct < 4; ct++){
            int c0l = w*64 + ct*16;
            int c0 = half*1024 + c0l;
            f16x8 bh[NF], bl[NF];
            #pragma unroll
            for (int kk = 0; kk < NF; kk++){
                bh[kk] = *(const f16x8*)(xhb + (size_t)(c0+lo)*KK + kk*32 + hi*8);
                bl[kk] = *(const f16x8*)(xlb + (size_t)(c0+lo)*KK + kk*32 + hi*8);
            }
            f32x4 acc = (f32x4){0.f,0.f,0.f,0.f};
            #pragma unroll
            for (int kk = 0; kk < NF; kk++) acc = __builtin_amdgcn_mfma_f32_16x16x32_f16(ah[kk], bh[kk], acc, 0, 0, 0);
            #pragma unroll
            for (int kk = 0; kk < NF; kk++) acc = __builtin_amdgcn_mfma_f32_16x16x32_f16(ah[kk], bl[kk], acc, 0, 0, 0);
            #pragma unroll
            for (int kk = 0; kk < NF; kk++) acc = __builtin_amdgcn_mfma_f32_16x16x32_f16(al[kk], bh[kk], acc, 0, 0, 0);
            float xm = xxb[c0 + lo];
            #pragma unroll
            for (int r = 0; r < 4; r++)
                Dt[(hi*4 + r)*DHALF + c0l + lo] = xn[r] + xm - 2.f*acc[r];
        }
        __syncthreads();
        // ---- bank this half's 16 keys/lane (row w)
        const float* Dr = Dt + w*DHALF;
        #pragma unroll
        for (int q = 0; q < 4; q++){
            float4 v = *(const float4*)(Dr + q*256 + l*4);
            int s0 = half*16 + 4*q;
            float f0 = fmaxf(v.x,0.f), f1 = fmaxf(v.y,0.f), f2 = fmaxf(v.z,0.f), f3 = fmaxf(v.w,0.f);
            key[s0+0] = (__float_as_uint(f0) & 0xFFFFFFE0u) | (unsigned)(s0+0);
            key[s0+1] = (__float_as_uint(f1) & 0xFFFFFFE0u) | (unsigned)(s0+1);
            key[s0+2] = (__float_as_uint(f2) & 0xFFFFFFE0u) | (unsigned)(s0+2);
            key[s0+3] = (__float_as_uint(f3) & 0xFFFFFFE0u) | (unsigned)(s0+3);
        }
        __syncthreads();
    }
    // ---- extraction over the 32 banked keys
    unsigned g[4];
    #pragma unroll
    for (int G = 0; G < 4; G++){
        unsigned mn = key[8*G];
        #pragma unroll
        for (int s = 1; s < 8; s++) mn = umn(mn, key[8*G+s]);
        g[G] = mn;
    }
    int* op = idxo + ((size_t)b*NPT + n0 + w)*KNN;
    for (int it = 0; it < KNN; ++it){
        unsigned lm = umn(umn(g[0],g[1]), umn(g[2],g[3]));
        unsigned wm = wave_min_sgpr(lm);          // SGPR: scalar slot/Gw below
        unsigned long long bal = __ballot(lm == wm);
        int L = __ffsll(bal) - 1;
        int slot = (int)(wm & 31u);
        if (l == 0) op[it] = (slot>>4)*1024 + ((slot>>2)&3)*256 + L*4 + (slot&3);
        int Gw = slot >> 3;
        bool iwin = (l == L);
        #pragma unroll
        for (int G = 0; G < 4; G++) if (G == Gw){   // scalar branch: one group only
            unsigned mn = 0xFFFFFFFFu;
            #pragma unroll
            for (int s = 8*G; s < 8*G+8; s++){
                unsigned kv = key[s];
                if (iwin && s == slot) kv = 0xFFFFFFFFu;
                key[s] = kv;
                mn = umn(mn, kv);
            }
            g[G] = mn;
        }
    }
}

// ---------------------------------------------------------------- per-stage projection (+xx norm, +fp16 copies, +hi/lo split)
template<int C>
__global__ __launch_bounds__(256) void k_proj(const float* __restrict__ src,
                                              const float* __restrict__ wAT, const float* __restrict__ wCT,
                                              const float* __restrict__ A, const float* __restrict__ Bv,
                                              float* __restrict__ zA, float* __restrict__ zC,
                                              _Float16* __restrict__ zAh, _Float16* __restrict__ zCh,
                                              _Float16* __restrict__ xh, _Float16* __restrict__ xl,
                                              float* __restrict__ xx){
    int wv = blockIdx.x*4 + (threadIdx.x>>6);
    int lane = threadIdx.x & 63;
    float wa[C], wc[C];
    #pragma unroll
    for (int c = 0; c < C; c++){ wa[c] = wAT[c*64+lane]; wc[c] = wCT[c*64+lane]; }
    float al = A[lane], be = Bv[lane];
    for (int p0 = 0; p0 < 4; p0++){
        int pt = wv*4 + p0;
        const float4* xr = (const float4*)(src + (size_t)pt*C);
        float sa = 0.f, sc = 0.f, sq = 0.f;
        #pragma unroll
        for (int i = 0; i < C/4; i++){
            float4 v = xr[i];
            sa += wa[4*i]*v.x + wa[4*i+1]*v.y + wa[4*i+2]*v.z + wa[4*i+3]*v.w;
            sc += wc[4*i]*v.x + wc[4*i+1]*v.y + wc[4*i+2]*v.z + wc[4*i+3]*v.w;
            sq += v.x*v.x + v.y*v.y + v.z*v.z + v.w*v.w;
        }
        float va = al*sa, vc = al*sc + be;
        zA[(size_t)pt*64 + lane] = va;
        zC[(size_t)pt*64 + lane] = vc;
        zAh[(size_t)pt*64 + lane] = (_Float16)va;
        zCh[(size_t)pt*64 + lane] = (_Float16)vc;
        if (lane == 0) xx[pt] = sq;
        if (C == 64){
            float xv = src[(size_t)pt*64 + lane];
            _Float16 h = (_Float16)xv;
            xh[(size_t)pt*64 + lane] = h;
            xl[(size_t)pt*64 + lane] = (_Float16)(xv - (float)h);
        }
    }
}

// ---------------------------------------------------------------- edge gather + maxpool (stages 1..3 only)
__global__ __launch_bounds__(256) void k_edgeg(const int* __restrict__ idxp,
                                               const float* __restrict__ zA, const float* __restrict__ zC,
                                               float* __restrict__ dst){
    int wv = blockIdx.x*4 + (threadIdx.x>>6);
    int lane = threadIdx.x & 63;
    for (int p0 = 0; p0 < 4; p0++){
        int pt = wv*4 + p0;
        int b = pt >> 11;
        float zc = zC[(size_t)pt*64 + lane];
        const int* ip = idxp + (size_t)pt*KNN;
        const float* zb = zA + ((size_t)b*NPT)*64;
        float mv = -3.4e38f;
        #pragma unroll
        for (int j = 0; j < KNN; j++){
            float v = lrl(zb[(size_t)ip[j]*64 + lane] + zc, 0.2f);
            mv = fmaxf(mv, v);
        }
        dst[(size_t)pt*64 + lane] = mv;
    }
}

// ---------------------------------------------------------------- block5: recompute y in-register, MFMA, bn5+lrelu(max)
__global__ __launch_bounds__(256) void k_block5(P p){
    __shared__ float HS[4][16*85];
    __shared__ _Float16 ZC[4][4][72];             // [stage][pt_local][64ch + pad]
    int tid = threadIdx.x;
    int wid = tid >> 6, l = tid & 63;
    int lo = l & 15, hi = l >> 4;
    int g = blockIdx.x;                           // 4096 groups of 4 points = 80 edges
    const size_t SS   = (size_t)NB*NPT*KNN;       // idx stage stride
    const size_t ZS   = (size_t)NB*NPT*64;        // zAh/zCh stage stride
    // coalesced zc staging: 4 stages x 4 pts x 64 halves = 1024 halves; 4 per thread
    {
        int q = tid * 4;
        int s = q >> 8, ptl = (q >> 6) & 3, c = q & 63;
        int pt = g*4 + ptl;
        *(f16x4*)&ZC[s][ptl][c] = *(const f16x4*)(p.zCh + (size_t)s*ZS + (size_t)pt*64 + c);
    }
    __syncthreads();
    f16x8 af[8];
    #pragma unroll
    for (int kk = 0; kk < 8; kk++)
        af[kk] = *(const f16x8*)(p.w5h + (wid*16 + lo)*256 + kk*32 + hi*8);
    // prefetch all 20 neighbor indices (breaks idx->gather serial chain)
    int mm[5][4];
    #pragma unroll
    for (int et = 0; et < 5; et++){
        int e = g*80 + et*16 + lo;
        #pragma unroll
        for (int s = 0; s < 4; s++) mm[et][s] = p.idx[(size_t)s*SS + e];
    }
    f32x4 acc[5];
    #pragma unroll
    for (int et = 0; et < 5; et++) acc[et] = (f32x4){0.f,0.f,0.f,0.f};
    #pragma unroll
    for (int et = 0; et < 5; et++){
        int e  = g*80 + et*16 + lo;
        int pt = e / 20;
        int b  = pt >> 11;
        int ptl = pt & 3;
        #pragma unroll
        for (int s = 0; s < 4; s++){
            int m = mm[et][s];
            const f16x8* za  = (const f16x8*)(p.zAh + (size_t)s*ZS + ((size_t)(b*NPT + m))*64 + hi*8);
            const f16x8* zcl = (const f16x8*)&ZC[s][ptl][hi*8];
            f16x8 y0 = lrl8(za[0] + zcl[0]);
            f16x8 y1 = lrl8(za[4] + zcl[4]);
            acc[et] = __builtin_amdgcn_mfma_f32_16x16x32_f16(af[2*s+0], y0, acc[et], 0, 0, 0);
            acc[et] = __builtin_amdgcn_mfma_f32_16x16x32_f16(af[2*s+1], y1, acc[et], 0, 0, 0);
        }
    }
    float* Hw = HS[wid];
    #pragma unroll
    for (int et = 0; et < 5; et++){
        #pragma unroll
        for (int r = 0; r < 4; r++)
            Hw[(hi*4 + r)*85 + et*16 + lo] = acc[et][r];
    }
    float mv = -3.4e38f;
    #pragma unroll
    for (int j = 0; j < KNN; j++)
        mv = fmaxf(mv, Hw[lo*85 + hi*20 + j]);
    int o = wid*16 + lo;
    int pt = g*4 + hi;
    float b5 = p.ab[576+o];
    p.h5T[(size_t)pt*64 + o] = lrl(mv + b5, 0.2f);
}

// ---------------------------------------------------------------- block6 conv + partial pools
__global__ __launch_bounds__(256) void k_block6(P p){
    int o = threadIdx.x;
    int ch = blockIdx.x, b = blockIdx.y;
    float w6r[64];
    #pragma unroll
    for (int c = 0; c < 64; c++) w6r[c] = p.w6T[c*256 + o];
    float a6 = p.ab[640+o], b6 = p.ab[896+o];
    float mv = -3.4e38f, sm = 0.f;
    for (int n = ch*128; n < ch*128 + 128; ++n){
        const float4* h4 = (const float4*)(p.h5T + ((size_t)b*NPT + n)*64);
        float t = 0.f;
        #pragma unroll
        for (int i = 0; i < 16; i++){
            float4 v = h4[i];
            t += w6r[4*i]*v.x + w6r[4*i+1]*v.y + w6r[4*i+2]*v.z + w6r[4*i+3]*v.w;
        }
        float y = lrl(a6*t + b6, 0.2f);
        mv = fmaxf(mv, y); sm += y;
    }
    p.pmax[((size_t)b*16 + ch)*256 + o] = mv;
    p.psum[((size_t)b*16 + ch)*256 + o] = sm;
}

// ---------------------------------------------------------------- final pool + FC head
__global__ __launch_bounds__(256) void k_head(P p){
    __shared__ float g[512], z1[256], z2[64];
    int b = blockIdx.x, o = threadIdx.x;
    float mv = -3.4e38f, sm = 0.f;
    for (int ch = 0; ch < 16; ++ch){
        mv = fmaxf(mv, p.pmax[((size_t)b*16+ch)*256 + o]);
        sm += p.psum[((size_t)b*16+ch)*256 + o];
    }
    g[o] = mv; g[256+o] = sm * (1.f/NPT);
    __syncthreads();
    float t = 0.f;
    for (int c = 0; c < 512; c++) t += g[c]*p.lw1T[c*256 + o];
    z1[o] = lrl(p.ab[1152+o]*t + p.ab[1408+o], 0.01f);
    __syncthreads();
    if (o < 64){
        float t2 = 0.f;
        for (int c = 0; c < 256; c++) t2 += z1[c]*p.lw2T[c*64 + o];
        z2[o] = lrl(p.ab[1664+o]*t2 + p.ab[1728+o], 0.01f);
    }
    __syncthreads();
    if (o < CLS){
        float t3 = p.lb3[o];
        for (int c = 0; c < 64; c++) t3 += z2[c]*p.lw3[o*64 + c];
        p.out[(size_t)b*CLS + o] = t3;
    }
}

// ---------------------------------------------------------------- host
extern "C" void kernel_launch(void* const* d_in, const int* in_sizes, int n_in,
                              void* d_out, int out_size, void* d_ws, size_t ws_size,
                              hipStream_t stream){
    P p;
    p.x   = (const float*)d_in[0];
    p.w1  = (const float*)d_in[1];  p.bn1 = (const float*)d_in[2];
    p.w2  = (const float*)d_in[3];  p.bn2 = (const float*)d_in[4];
    p.w3  = (const float*)d_in[5];  p.bn3 = (const float*)d_in[6];
    p.w4  = (const float*)d_in[7];  p.bn4 = (const float*)d_in[8];
    p.w5  = (const float*)d_in[9];  p.bn5 = (const float*)d_in[10];
    p.w6  = (const float*)d_in[11]; p.bn6 = (const float*)d_in[12];
    p.lw1 = (const float*)d_in[13]; p.lb1 = (const float*)d_in[14]; p.lbn1 = (const float*)d_in[15];
    p.lw2 = (const float*)d_in[16]; p.lb2 = (const float*)d_in[17]; p.lbn2 = (const float*)d_in[18];
    p.lw3 = (const float*)d_in[19]; p.lb3 = (const float*)d_in[20];
    p.out = (float*)d_out;

    float* w = (float*)d_ws;
    size_t off = 0;
    auto alloc = [&](size_t n)->float*{ float* r = w + off; off += (n + 63) & ~(size_t)63; return r; };
    p.xT0  = alloc((size_t)NB*NPT*4);
    p.xT1  = alloc((size_t)NB*NPT*64);
    p.xT2  = alloc((size_t)NB*NPT*64);
    p.xT3  = alloc((size_t)NB*NPT*64);
    p.h5T  = alloc((size_t)NB*NPT*64);
    p.xx   = alloc((size_t)NB*NPT);
    p.idx  = (int*)alloc((size_t)4*NB*NPT*KNN);
    p.wAT1 = alloc(256);  p.wCT1 = alloc(256);
    p.wAT2 = alloc(4096); p.wCT2 = alloc(4096);
    p.wAT3 = alloc(4096); p.wCT3 = alloc(4096);
    p.wAT4 = alloc(4096); p.wCT4 = alloc(4096);
    p.ab   = alloc(1792);
    p.zA   = alloc((size_t)NB*NPT*64);
    p.zC   = alloc((size_t)NB*NPT*64);
    const size_t ZS = (size_t)NB*NPT*64;              // fp16 elements per stage
    p.zAh = (_Float16*)alloc(4*ZS/2);
    p.zCh = (_Float16*)alloc(4*ZS/2);
    p.xh  = (_Float16*)alloc(ZS/2);
    p.xl  = (_Float16*)alloc(ZS/2);
    p.xh0 = (_Float16*)alloc((size_t)NB*NPT*32/2);
    p.xl0 = (_Float16*)alloc((size_t)NB*NPT*32/2);
    p.w5h = (_Float16*)alloc(64*256/2);
    p.w6T  = alloc(16384);
    p.lw1T = alloc(131072); p.lw2T = alloc(16384);
    p.pmax = alloc((size_t)NB*16*256);
    p.psum = alloc((size_t)NB*16*256);

    k_prep<<<64, 256, 0, stream>>>(p);
    const size_t SS = (size_t)NB*NPT*KNN;
    for (int s = 0; s < 4; s++){
        const float* src = (s==0) ? p.xT0 : (s==1 ? p.xT1 : (s==2 ? p.xT2 : p.xT3));
        int* idxs = p.idx + (size_t)s*SS;
        _Float16* zAh = p.zAh + (size_t)s*ZS;
        _Float16* zCh = p.zCh + (size_t)s*ZS;
        if (s == 0)      k_proj<4 ><<<NB*NPT/16, 256, 0, stream>>>(src, p.wAT1, p.wCT1, p.ab+0,   p.ab+64,  p.zA, p.zC, zAh, zCh, p.xh, p.xl, p.xx);
        else if (s == 1) k_proj<64><<<NB*NPT/16, 256, 0, stream>>>(src, p.wAT2, p.wCT2, p.ab+128, p.ab+192, p.zA, p.zC, zAh, zCh, p.xh, p.xl, p.xx);
        else if (s == 2) k_proj<64><<<NB*NPT/16, 256, 0, stream>>>(src, p.wAT3, p.wCT3, p.ab+256, p.ab+320, p.zA, p.zC, zAh, zCh, p.xh, p.xl, p.xx);
        else             k_proj<64><<<NB*NPT/16, 256, 0, stream>>>(src, p.wAT4, p.wCT4, p.ab+384, p.ab+448, p.zA, p.zC, zAh, zCh, p.xh, p.xl, p.xx);
        if (s == 0) k_knn<32><<<NB*NPT/16, 1024, 0, stream>>>(p.xh0, p.xl0, p.xx, idxs);
        else        k_knn<64><<<NB*NPT/16, 1024, 0, stream>>>(p.xh,  p.xl,  p.xx, idxs);
        if (s == 0)      k_edgeg<<<NB*NPT/16, 256, 0, stream>>>(idxs, p.zA, p.zC, p.xT1);
        else if (s == 1) k_edgeg<<<NB*NPT/16, 256, 0, stream>>>(idxs, p.zA, p.zC, p.xT2);
        else if (s == 2) k_edgeg<<<NB*NPT/16, 256, 0, stream>>>(idxs, p.zA, p.zC, p.xT3);
        // s==3: x4 unused -> no edgeg; only idx4 + zAh4/zCh4 needed by block5
    }
    k_block5<<<NB*NPT/4, 256, 0, stream>>>(p);
    k_block6<<<dim3(16, NB), 256, 0, stream>>>(p);
    k_head<<<NB, 256, 0, stream>>>(p);
}

// Round 11
// 649.436 us; speedup vs baseline: 1.8545x; 1.0790x over previous
//
#include <hip/hip_runtime.h>

#define NB   8
#define NPT  2048
#define KNN  20
#define CLS  40
#define EPSBN 1e-5f
#define DHALF 1028   // padded LDS row stride for half-width D tile (floats)

typedef _Float16 f16x8 __attribute__((ext_vector_type(8)));
typedef _Float16 f16x4 __attribute__((ext_vector_type(4)));
typedef short    short8 __attribute__((ext_vector_type(8)));
typedef float    f32x4 __attribute__((ext_vector_type(4)));

struct P {
    const float *x,*w1,*bn1,*w2,*bn2,*w3,*bn3,*w4,*bn4,*w5,*bn5,*w6,*bn6;
    const float *lw1,*lb1,*lbn1,*lw2,*lb2,*lbn2,*lw3,*lb3;
    float *xT0,*xT1,*xT2,*xT3,*h5T,*xx;
    int   *idx;                       // [4][B*N][KNN]
    float *wAT1,*wCT1,*wAT2,*wCT2,*wAT3,*wCT3,*wAT4,*wCT4;
    float *ab;                        // packed alpha/beta, see offsets below
    float *zA,*zC;                    // per-stage fp32 projections (scratch, reused)
    _Float16 *zAh,*zCh;               // fp16 projections kept per stage: [4][B*N][64]
    _Float16 *xh,*xl;                 // fp16 hi/lo split of current stage src [pt][64] (scratch)
    _Float16 *xh0,*xl0;               // stage-0 padded split [pt][32]
    _Float16 *w5h;                    // a5-prescaled W5, fp16 (64x256)
    float *w6T,*lw1T,*lw2T;
    float *pmax,*psum;
    float *out;
};
// ab offsets: a1=0 b1=64 a2=128 b2=192 a3=256 b3=320 a4=384 b4=448
//             a5=512 b5=576 a6=640(256) b6=896(256) ah1=1152(256) bh1=1408(256)
//             ah2=1664(64) bh2=1728(64)   total 1792

__device__ __forceinline__ float lrl(float v, float s){ return v >= 0.f ? v : s*v; }
__device__ __forceinline__ unsigned umn(unsigned a, unsigned b){ return a < b ? a : b; }

// wave64 min -> SGPR via DPP prefix-min (row_shr 1/2/4/8, row_bcast15/31) + readlane(63)
__device__ __forceinline__ unsigned wave_min_sgpr(unsigned v){
    unsigned t;
    t = (unsigned)__builtin_amdgcn_update_dpp((int)v,(int)v,0x111,0xF,0xF,false); v = umn(v,t);
    t = (unsigned)__builtin_amdgcn_update_dpp((int)v,(int)v,0x112,0xF,0xF,false); v = umn(v,t);
    t = (unsigned)__builtin_amdgcn_update_dpp((int)v,(int)v,0x114,0xF,0xF,false); v = umn(v,t);
    t = (unsigned)__builtin_amdgcn_update_dpp((int)v,(int)v,0x118,0xF,0xF,false); v = umn(v,t);
    t = (unsigned)__builtin_amdgcn_update_dpp((int)v,(int)v,0x142,0xF,0xF,false); v = umn(v,t);
    t = (unsigned)__builtin_amdgcn_update_dpp((int)v,(int)v,0x143,0xF,0xF,false); v = umn(v,t);
    return (unsigned)__builtin_amdgcn_readlane((int)v, 63);
}

// packed fp16 leaky-relu(0.2) via sign-mask select
__device__ __forceinline__ f16x8 lrl8(f16x8 v){
    f16x8 t = v * (_Float16)0.2f;
    short8 m = ((short8)v) >> 15;
    short8 r = (((short8)t) & m) | (((short8)v) & ~m);
    return (f16x8)r;
}

// ---------------------------------------------------------------- prep
__global__ __launch_bounds__(256) void k_prep(P p){
    int gid = blockIdx.x*256 + threadIdx.x;
    int gsz = gridDim.x*256;
    for (int i = gid; i < NB*NPT*4; i += gsz){
        int c = i & 3; int pt = i >> 2; int n = pt & (NPT-1); int b = pt >> 11;
        p.xT0[i] = (c < 3) ? p.x[((size_t)b*3 + c)*NPT + n] : 0.f;
    }
    // stage-0 split, padded to K=32: [pt][32]
    for (int i = gid; i < NB*NPT*32; i += gsz){
        int c = i & 31; int pt = i >> 5; int n = pt & (NPT-1); int b = pt >> 11;
        float xv = (c < 3) ? p.x[((size_t)b*3 + c)*NPT + n] : 0.f;
        _Float16 h = (_Float16)xv;
        p.xh0[i] = h;
        p.xl0[i] = (_Float16)(xv - (float)h);
    }
    for (int e = gid; e < 4*64; e += gsz){
        int c = e >> 6, o = e & 63;
        float a  = (c < 3) ? p.w1[o*6 + c]     : 0.f;
        float bw = (c < 3) ? p.w1[o*6 + 3 + c] : 0.f;
        p.wAT1[e] = a; p.wCT1[e] = bw - a;
    }
    #pragma unroll
    for (int k = 0; k < 3; ++k){
        const float* wsrc = (k==0) ? p.w2 : (k==1 ? p.w3 : p.w4);
        float* wa = (k==0) ? p.wAT2 : (k==1 ? p.wAT3 : p.wAT4);
        float* wc = (k==0) ? p.wCT2 : (k==1 ? p.wCT3 : p.wCT4);
        for (int e = gid; e < 64*64; e += gsz){
            int c = e >> 6, o = e & 63;
            float a = wsrc[o*128 + c];
            wa[e] = a;
            wc[e] = wsrc[o*128 + 64 + c] - a;
        }
    }
    for (int e = gid; e < 64*256; e += gsz){
        int o = e >> 8;
        float a5 = p.bn5[o] * rsqrtf(p.bn5[3*64 + o] + EPSBN);
        p.w5h[e] = (_Float16)(a5 * p.w5[e]);
    }
    for (int e = gid; e < 64*256;  e += gsz){ int c=e>>8, o=e&255; p.w6T[e]  = p.w6[o*64+c];   }
    for (int e = gid; e < 512*256; e += gsz){ int c=e>>8, o=e&255; p.lw1T[e] = p.lw1[o*512+c]; }
    for (int e = gid; e < 256*64;  e += gsz){ int c=e>>6, o=e&63;  p.lw2T[e] = p.lw2[o*256+c]; }
    auto ab = [&](const float* bn, int C, float* A, float* Bv, const float* lb){
        for (int c = gid; c < C; c += gsz){
            float s = bn[c], bb = bn[C+c], m = bn[2*C+c], v = bn[3*C+c];
            float al = s * rsqrtf(v + EPSBN);
            float be = bb - m*al;
            if (lb) be += al*lb[c];
            A[c] = al; Bv[c] = be;
        }
    };
    ab(p.bn1, 64,  p.ab+0,    p.ab+64,   nullptr);
    ab(p.bn2, 64,  p.ab+128,  p.ab+192,  nullptr);
    ab(p.bn3, 64,  p.ab+256,  p.ab+320,  nullptr);
    ab(p.bn4, 64,  p.ab+384,  p.ab+448,  nullptr);
    ab(p.bn5, 64,  p.ab+512,  p.ab+576,  nullptr);
    ab(p.bn6, 256, p.ab+640,  p.ab+896,  nullptr);
    ab(p.lbn1,256, p.ab+1152, p.ab+1408, p.lb1);
    ab(p.lbn2,64,  p.ab+1664, p.ab+1728, p.lb2);
}

// ---------------------------------------------------------------- fused kNN: two-half dist (split-fp16 MFMA) + top-20
// block = 16 rows of one batch, 512 threads (8 waves). LDS = 16x1024 half-tile (65.8 KB) -> 2 blocks/CU,
// VGPR cap 128 (4 waves/SIMD) -> no spill. dist: wave w covers 128 cols/half; select: wave w owns rows 2w,2w+1.
template<int KK>
__global__ __launch_bounds__(512, 4) void k_knn(const _Float16* __restrict__ xh, const _Float16* __restrict__ xl,
                                                const float* __restrict__ xx, int* __restrict__ idxo){
    __shared__ float Dt[16*DHALF];
    int w = threadIdx.x >> 6, l = threadIdx.x & 63;
    int lo = l & 15, hi = l >> 4;
    int id = blockIdx.x;
    int b = id & 7;                       // XCD batch pinning
    int n0 = (id >> 3) * 16;
    const _Float16* xhb = xh + (size_t)b*NPT*KK;
    const _Float16* xlb = xl + (size_t)b*NPT*KK;
    const float* xxb = xx + (size_t)b*NPT;
    constexpr int NF = KK/32;
    f16x8 ah[NF], al[NF];
    #pragma unroll
    for (int kk = 0; kk < NF; kk++){
        ah[kk] = *(const f16x8*)(xhb + (size_t)(n0+lo)*KK + kk*32 + hi*8);
        al[kk] = *(const f16x8*)(xlb + (size_t)(n0+lo)*KK + kk*32 + hi*8);
    }
    float xn[4];
    #pragma unroll
    for (int r = 0; r < 4; r++) xn[r] = xxb[n0 + hi*4 + r];
    unsigned key[2][32];
    #pragma unroll
    for (int half = 0; half < 2; half++){
        // ---- dist: wave w covers local cols [w*128, w*128+128) of this half
        #pragma unroll
        for (int ct = 0; ct < 8; ct++){
            int c0l = w*128 + ct*16;
            int c0 = half*1024 + c0l;
            f16x8 bh[NF], bl[NF];
            #pragma unroll
            for (int kk = 0; kk < NF; kk++){
                bh[kk] = *(const f16x8*)(xhb + (size_t)(c0+lo)*KK + kk*32 + hi*8);
                bl[kk] = *(const f16x8*)(xlb + (size_t)(c0+lo)*KK + kk*32 + hi*8);
            }
            f32x4 acc = (f32x4){0.f,0.f,0.f,0.f};
            #pragma unroll
            for (int kk = 0; kk < NF; kk++) acc = __builtin_amdgcn_mfma_f32_16x16x32_f16(ah[kk], bh[kk], acc, 0, 0, 0);
            #pragma unroll
            for (int kk = 0; kk < NF; kk++) acc = __builtin_amdgcn_mfma_f32_16x16x32_f16(ah[kk], bl[kk], acc, 0, 0, 0);
            #pragma unroll
            for (int kk = 0; kk < NF; kk++) acc = __builtin_amdgcn_mfma_f32_16x16x32_f16(al[kk], bh[kk], acc, 0, 0, 0);
            float xm = xxb[c0 + lo];
            #pragma unroll
            for (int r = 0; r < 4; r++)
                Dt[(hi*4 + r)*DHALF + c0l + lo] = xn[r] + xm - 2.f*acc[r];
        }
        __syncthreads();
        // ---- bank this half's 16 keys/lane for rows 2w, 2w+1
        #pragma unroll
        for (int rr = 0; rr < 2; rr++){
            const float* Dr = Dt + (w*2 + rr)*DHALF;
            #pragma unroll
            for (int q = 0; q < 4; q++){
                float4 v = *(const float4*)(Dr + q*256 + l*4);
                int s0 = half*16 + 4*q;
                float f0 = fmaxf(v.x,0.f), f1 = fmaxf(v.y,0.f), f2 = fmaxf(v.z,0.f), f3 = fmaxf(v.w,0.f);
                key[rr][s0+0] = (__float_as_uint(f0) & 0xFFFFFFE0u) | (unsigned)(s0+0);
                key[rr][s0+1] = (__float_as_uint(f1) & 0xFFFFFFE0u) | (unsigned)(s0+1);
                key[rr][s0+2] = (__float_as_uint(f2) & 0xFFFFFFE0u) | (unsigned)(s0+2);
                key[rr][s0+3] = (__float_as_uint(f3) & 0xFFFFFFE0u) | (unsigned)(s0+3);
            }
        }
        __syncthreads();
    }
    // ---- extraction: 2 rows interleaved (independent DPP chains)
    unsigned g[2][4];
    int* opp[2];
    #pragma unroll
    for (int rr = 0; rr < 2; rr++){
        #pragma unroll
        for (int G = 0; G < 4; G++){
            unsigned mn = key[rr][8*G];
            #pragma unroll
            for (int s = 1; s < 8; s++) mn = umn(mn, key[rr][8*G+s]);
            g[rr][G] = mn;
        }
        opp[rr] = idxo + ((size_t)b*NPT + n0 + w*2 + rr)*KNN;
    }
    for (int it = 0; it < KNN; ++it){
        unsigned lm0 = umn(umn(g[0][0],g[0][1]), umn(g[0][2],g[0][3]));
        unsigned lm1 = umn(umn(g[1][0],g[1][1]), umn(g[1][2],g[1][3]));
        unsigned wm[2];
        wm[0] = wave_min_sgpr(lm0);
        wm[1] = wave_min_sgpr(lm1);
        unsigned long long bal0 = __ballot(lm0 == wm[0]);
        unsigned long long bal1 = __ballot(lm1 == wm[1]);
        int L[2] = {__ffsll(bal0) - 1, __ffsll(bal1) - 1};
        #pragma unroll
        for (int rr = 0; rr < 2; rr++){
            int slot = (int)(wm[rr] & 31u);        // scalar
            if (l == 0) opp[rr][it] = (slot>>4)*1024 + ((slot>>2)&3)*256 + L[rr]*4 + (slot&3);
            int Gw = slot >> 3;
            bool iwin = (l == L[rr]);
            #pragma unroll
            for (int G = 0; G < 4; G++) if (G == Gw){   // scalar branch: one group only
                unsigned mn = 0xFFFFFFFFu;
                #pragma unroll
                for (int s = 8*G; s < 8*G+8; s++){
                    unsigned kv = key[rr][s];
                    if (iwin && s == slot) kv = 0xFFFFFFFFu;
                    key[rr][s] = kv;
                    mn = umn(mn, kv);
                }
                g[rr][G] = mn;
            }
        }
    }
}

// ---------------------------------------------------------------- per-stage projection (+xx norm, +fp16 copies, +hi/lo split)
template<int C>
__global__ __launch_bounds__(256) void k_proj(const float* __restrict__ src,
                                              const float* __restrict__ wAT, const float* __restrict__ wCT,
                                              const float* __restrict__ A, const float* __restrict__ Bv,
                                              float* __restrict__ zA, float* __restrict__ zC,
                                              _Float16* __restrict__ zAh, _Float16* __restrict__ zCh,
                                              _Float16* __restrict__ xh, _Float16* __restrict__ xl,
                                              float* __restrict__ xx){
    int wv = blockIdx.x*4 + (threadIdx.x>>6);
    int lane = threadIdx.x & 63;
    float wa[C], wc[C];
    #pragma unroll
    for (int c = 0; c < C; c++){ wa[c] = wAT[c*64+lane]; wc[c] = wCT[c*64+lane]; }
    float al = A[lane], be = Bv[lane];
    for (int p0 = 0; p0 < 4; p0++){
        int pt = wv*4 + p0;
        const float4* xr = (const float4*)(src + (size_t)pt*C);
        float sa = 0.f, sc = 0.f, sq = 0.f;
        #pragma unroll
        for (int i = 0; i < C/4; i++){
            float4 v = xr[i];
            sa += wa[4*i]*v.x + wa[4*i+1]*v.y + wa[4*i+2]*v.z + wa[4*i+3]*v.w;
            sc += wc[4*i]*v.x + wc[4*i+1]*v.y + wc[4*i+2]*v.z + wc[4*i+3]*v.w;
            sq += v.x*v.x + v.y*v.y + v.z*v.z + v.w*v.w;
        }
        float va = al*sa, vc = al*sc + be;
        zA[(size_t)pt*64 + lane] = va;
        zC[(size_t)pt*64 + lane] = vc;
        zAh[(size_t)pt*64 + lane] = (_Float16)va;
        zCh[(size_t)pt*64 + lane] = (_Float16)vc;
        if (lane == 0) xx[pt] = sq;
        if (C == 64){
            float xv = src[(size_t)pt*64 + lane];
            _Float16 h = (_Float16)xv;
            xh[(size_t)pt*64 + lane] = h;
            xl[(size_t)pt*64 + lane] = (_Float16)(xv - (float)h);
        }
    }
}

// ---------------------------------------------------------------- edge gather + maxpool (stages 1..3 only)
__global__ __launch_bounds__(256) void k_edgeg(const int* __restrict__ idxp,
                                               const float* __restrict__ zA, const float* __restrict__ zC,
                                               float* __restrict__ dst){
    int wv = blockIdx.x*4 + (threadIdx.x>>6);
    int lane = threadIdx.x & 63;
    for (int p0 = 0; p0 < 4; p0++){
        int pt = wv*4 + p0;
        int b = pt >> 11;
        float zc = zC[(size_t)pt*64 + lane];
        const int* ip = idxp + (size_t)pt*KNN;
        const float* zb = zA + ((size_t)b*NPT)*64;
        float mv = -3.4e38f;
        #pragma unroll
        for (int j = 0; j < KNN; j++){
            float v = lrl(zb[(size_t)ip[j]*64 + lane] + zc, 0.2f);
            mv = fmaxf(mv, v);
        }
        dst[(size_t)pt*64 + lane] = mv;
    }
}

// ---------------------------------------------------------------- block5: recompute y in-register, MFMA, bn5+lrelu(max)
__global__ __launch_bounds__(256) void k_block5(P p){
    __shared__ float HS[4][16*85];
    __shared__ _Float16 ZC[4][4][72];             // [stage][pt_local][64ch + pad]
    int tid = threadIdx.x;
    int wid = tid >> 6, l = tid & 63;
    int lo = l & 15, hi = l >> 4;
    int g = blockIdx.x;                           // 4096 groups of 4 points = 80 edges
    const size_t SS   = (size_t)NB*NPT*KNN;       // idx stage stride
    const size_t ZS   = (size_t)NB*NPT*64;        // zAh/zCh stage stride
    // coalesced zc staging: 4 stages x 4 pts x 64 halves = 1024 halves; 4 per thread
    {
        int q = tid * 4;
        int s = q >> 8, ptl = (q >> 6) & 3, c = q & 63;
        int pt = g*4 + ptl;
        *(f16x4*)&ZC[s][ptl][c] = *(const f16x4*)(p.zCh + (size_t)s*ZS + (size_t)pt*64 + c);
    }
    __syncthreads();
    f16x8 af[8];
    #pragma unroll
    for (int kk = 0; kk < 8; kk++)
        af[kk] = *(const f16x8*)(p.w5h + (wid*16 + lo)*256 + kk*32 + hi*8);
    // prefetch all 20 neighbor indices (breaks idx->gather serial chain)
    int mm[5][4];
    #pragma unroll
    for (int et = 0; et < 5; et++){
        int e = g*80 + et*16 + lo;
        #pragma unroll
        for (int s = 0; s < 4; s++) mm[et][s] = p.idx[(size_t)s*SS + e];
    }
    f32x4 acc[5];
    #pragma unroll
    for (int et = 0; et < 5; et++) acc[et] = (f32x4){0.f,0.f,0.f,0.f};
    #pragma unroll
    for (int et = 0; et < 5; et++){
        int e  = g*80 + et*16 + lo;
        int pt = e / 20;
        int b  = pt >> 11;
        int ptl = pt & 3;
        #pragma unroll
        for (int s = 0; s < 4; s++){
            int m = mm[et][s];
            const f16x8* za  = (const f16x8*)(p.zAh + (size_t)s*ZS + ((size_t)(b*NPT + m))*64 + hi*8);
            const f16x8* zcl = (const f16x8*)&ZC[s][ptl][hi*8];
            f16x8 y0 = lrl8(za[0] + zcl[0]);
            f16x8 y1 = lrl8(za[4] + zcl[4]);
            acc[et] = __builtin_amdgcn_mfma_f32_16x16x32_f16(af[2*s+0], y0, acc[et], 0, 0, 0);
            acc[et] = __builtin_amdgcn_mfma_f32_16x16x32_f16(af[2*s+1], y1, acc[et], 0, 0, 0);
        }
    }
    float* Hw = HS[wid];
    #pragma unroll
    for (int et = 0; et < 5; et++){
        #pragma unroll
        for (int r = 0; r < 4; r++)
            Hw[(hi*4 + r)*85 + et*16 + lo] = acc[et][r];
    }
    float mv = -3.4e38f;
    #pragma unroll
    for (int j = 0; j < KNN; j++)
        mv = fmaxf(mv, Hw[lo*85 + hi*20 + j]);
    int o = wid*16 + lo;
    int pt = g*4 + hi;
    float b5 = p.ab[576+o];
    p.h5T[(size_t)pt*64 + o] = lrl(mv + b5, 0.2f);
}

// ---------------------------------------------------------------- block6 conv + partial pools
__global__ __launch_bounds__(256) void k_block6(P p){
    int o = threadIdx.x;
    int ch = blockIdx.x, b = blockIdx.y;
    float w6r[64];
    #pragma unroll
    for (int c = 0; c < 64; c++) w6r[c] = p.w6T[c*256 + o];
    float a6 = p.ab[640+o], b6 = p.ab[896+o];
    float mv = -3.4e38f, sm = 0.f;
    for (int n = ch*128; n < ch*128 + 128; ++n){
        const float4* h4 = (const float4*)(p.h5T + ((size_t)b*NPT + n)*64);
        float t = 0.f;
        #pragma unroll
        for (int i = 0; i < 16; i++){
            float4 v = h4[i];
            t += w6r[4*i]*v.x + w6r[4*i+1]*v.y + w6r[4*i+2]*v.z + w6r[4*i+3]*v.w;
        }
        float y = lrl(a6*t + b6, 0.2f);
        mv = fmaxf(mv, y); sm += y;
    }
    p.pmax[((size_t)b*16 + ch)*256 + o] = mv;
    p.psum[((size_t)b*16 + ch)*256 + o] = sm;
}

// ---------------------------------------------------------------- final pool + FC head
__global__ __launch_bounds__(256) void k_head(P p){
    __shared__ float g[512], z1[256], z2[64];
    int b = blockIdx.x, o = threadIdx.x;
    float mv = -3.4e38f, sm = 0.f;
    for (int ch = 0; ch < 16; ++ch){
        mv = fmaxf(mv, p.pmax[((size_t)b*16+ch)*256 + o]);
        sm += p.psum[((size_t)b*16+ch)*256 + o];
    }
    g[o] = mv; g[256+o] = sm * (1.f/NPT);
    __syncthreads();
    float t = 0.f;
    for (int c = 0; c < 512; c++) t += g[c]*p.lw1T[c*256 + o];
    z1[o] = lrl(p.ab[1152+o]*t + p.ab[1408+o], 0.01f);
    __syncthreads();
    if (o < 64){
        float t2 = 0.f;
        for (int c = 0; c < 256; c++) t2 += z1[c]*p.lw2T[c*64 + o];
        z2[o] = lrl(p.ab[1664+o]*t2 + p.ab[1728+o], 0.01f);
    }
    __syncthreads();
    if (o < CLS){
        float t3 = p.lb3[o];
        for (int c = 0; c < 64; c++) t3 += z2[c]*p.lw3[o*64 + c];
        p.out[(size_t)b*CLS + o] = t3;
    }
}

// ---------------------------------------------------------------- host
extern "C" void kernel_launch(void* const* d_in, const int* in_sizes, int n_in,
                              void* d_out, int out_size, void* d_ws, size_t ws_size,
                              hipStream_t stream){
    P p;
    p.x   = (const float*)d_in[0];
    p.w1  = (const float*)d_in[1];  p.bn1 = (const float*)d_in[2];
    p.w2  = (const float*)d_in[3];  p.bn2 = (const float*)d_in[4];
    p.w3  = (const float*)d_in[5];  p.bn3 = (const float*)d_in[6];
    p.w4  = (const float*)d_in[7];  p.bn4 = (const float*)d_in[8];
    p.w5  = (const float*)d_in[9];  p.bn5 = (const float*)d_in[10];
    p.w6  = (const float*)d_in[11]; p.bn6 = (const float*)d_in[12];
    p.lw1 = (const float*)d_in[13]; p.lb1 = (const float*)d_in[14]; p.lbn1 = (const float*)d_in[15];
    p.lw2 = (const float*)d_in[16]; p.lb2 = (const float*)d_in[17]; p.lbn2 = (const float*)d_in[18];
    p.lw3 = (const float*)d_in[19]; p.lb3 = (const float*)d_in[20];
    p.out = (float*)d_out;

    float* w = (float*)d_ws;
    size_t off = 0;
    auto alloc = [&](size_t n)->float*{ float* r = w + off; off += (n + 63) & ~(size_t)63; return r; };
    p.xT0  = alloc((size_t)NB*NPT*4);
    p.xT1  = alloc((size_t)NB*NPT*64);
    p.xT2  = alloc((size_t)NB*NPT*64);
    p.xT3  = alloc((size_t)NB*NPT*64);
    p.h5T  = alloc((size_t)NB*NPT*64);
    p.xx   = alloc((size_t)NB*NPT);
    p.idx  = (int*)alloc((size_t)4*NB*NPT*KNN);
    p.wAT1 = alloc(256);  p.wCT1 = alloc(256);
    p.wAT2 = alloc(4096); p.wCT2 = alloc(4096);
    p.wAT3 = alloc(4096); p.wCT3 = alloc(4096);
    p.wAT4 = alloc(4096); p.wCT4 = alloc(4096);
    p.ab   = alloc(1792);
    p.zA   = alloc((size_t)NB*NPT*64);
    p.zC   = alloc((size_t)NB*NPT*64);
    const size_t ZS = (size_t)NB*NPT*64;              // fp16 elements per stage
    p.zAh = (_Float16*)alloc(4*ZS/2);
    p.zCh = (_Float16*)alloc(4*ZS/2);
    p.xh  = (_Float16*)alloc(ZS/2);
    p.xl  = (_Float16*)alloc(ZS/2);
    p.xh0 = (_Float16*)alloc((size_t)NB*NPT*32/2);
    p.xl0 = (_Float16*)alloc((size_t)NB*NPT*32/2);
    p.w5h = (_Float16*)alloc(64*256/2);
    p.w6T  = alloc(16384);
    p.lw1T = alloc(131072); p.lw2T = alloc(16384);
    p.pmax = alloc((size_t)NB*16*256);
    p.psum = alloc((size_t)NB*16*256);

    k_prep<<<64, 256, 0, stream>>>(p);
    const size_t SS = (size_t)NB*NPT*KNN;
    for (int s = 0; s < 4; s++){
        const float* src = (s==0) ? p.xT0 : (s==1 ? p.xT1 : (s==2 ? p.xT2 : p.xT3));
        int* idxs = p.idx + (size_t)s*SS;
        _Float16* zAh = p.zAh + (size_t)s*ZS;
        _Float16* zCh = p.zCh + (size_t)s*ZS;
        if (s == 0)      k_proj<4 ><<<NB*NPT/16, 256, 0, stream>>>(src, p.wAT1, p.wCT1, p.ab+0,   p.ab+64,  p.zA, p.zC, zAh, zCh, p.xh, p.xl, p.xx);
        else if (s == 1) k_proj<64><<<NB*NPT/16, 256, 0, stream>>>(src, p.wAT2, p.wCT2, p.ab+128, p.ab+192, p.zA, p.zC, zAh, zCh, p.xh, p.xl, p.xx);
        else if (s == 2) k_proj<64><<<NB*NPT/16, 256, 0, stream>>>(src, p.wAT3, p.wCT3, p.ab+256, p.ab+320, p.zA, p.zC, zAh, zCh, p.xh, p.xl, p.xx);
        else             k_proj<64><<<NB*NPT/16, 256, 0, stream>>>(src, p.wAT4, p.wCT4, p.ab+384, p.ab+448, p.zA, p.zC, zAh, zCh, p.xh, p.xl, p.xx);
        if (s == 0) k_knn<32><<<NB*NPT/16, 512, 0, stream>>>(p.xh0, p.xl0, p.xx, idxs);
        else        k_knn<64><<<NB*NPT/16, 512, 0, stream>>>(p.xh,  p.xl,  p.xx, idxs);
        if (s == 0)      k_edgeg<<<NB*NPT/16, 256, 0, stream>>>(idxs, p.zA, p.zC, p.xT1);
        else if (s == 1) k_edgeg<<<NB*NPT/16, 256, 0, stream>>>(idxs, p.zA, p.zC, p.xT2);
        else if (s == 2) k_edgeg<<<NB*NPT/16, 256, 0, stream>>>(idxs, p.zA, p.zC, p.xT3);
        // s==3: x4 unused -> no edgeg; only idx4 + zAh4/zCh4 needed by block5
    }
    k_block5<<<NB*NPT/4, 256, 0, stream>>>(p);
    k_block6<<<dim3(16, NB), 256, 0, stream>>>(p);
    k_head<<<NB, 256, 0, stream>>>(p);
}

// Round 12
// 625.673 us; speedup vs baseline: 1.9250x; 1.0380x over previous
//
#include <hip/hip_runtime.h>

#define NB   8
#define NPT  2048
#define KNN  20
#define CLS  40
#define EPSBN 1e-5f
#define DHALF 1028   // padded LDS row stride for half-width D tile (floats)

typedef _Float16 f16x8 __attribute__((ext_vector_type(8)));
typedef _Float16 f16x4 __attribute__((ext_vector_type(4)));
typedef short    short8 __attribute__((ext_vector_type(8)));
typedef float    f32x4 __attribute__((ext_vector_type(4)));

struct P {
    const float *x,*w1,*bn1,*w2,*bn2,*w3,*bn3,*w4,*bn4,*w5,*bn5,*w6,*bn6;
    const float *lw1,*lb1,*lbn1,*lw2,*lb2,*lbn2,*lw3,*lb3;
    float *xT0,*xT1,*xT2,*xT3,*h5T,*xx;
    int   *idx;                       // [4][B*N][KNN]
    float *wAT1,*wCT1,*wAT2,*wCT2,*wAT3,*wCT3,*wAT4,*wCT4;
    float *ab;                        // packed alpha/beta, see offsets below
    float *zA,*zC;                    // per-stage fp32 projections (scratch, reused)
    _Float16 *zAh,*zCh;               // fp16 projections kept per stage: [4][B*N][64]
    _Float16 *xh,*xl;                 // fp16 hi/lo split of current stage src [pt][64] (scratch)
    _Float16 *xh0,*xl0;               // stage-0 padded split [pt][32]
    _Float16 *w5h;                    // a5-prescaled W5, fp16 (64x256)
    float *w6T,*lw1T,*lw2T;
    float *pmax,*psum;
    float *out;
};
// ab offsets: a1=0 b1=64 a2=128 b2=192 a3=256 b3=320 a4=384 b4=448
//             a5=512 b5=576 a6=640(256) b6=896(256) ah1=1152(256) bh1=1408(256)
//             ah2=1664(64) bh2=1728(64)   total 1792

__device__ __forceinline__ float lrl(float v, float s){ return v >= 0.f ? v : s*v; }
__device__ __forceinline__ unsigned umn(unsigned a, unsigned b){ return a < b ? a : b; }

// wave64 min -> SGPR via DPP prefix-min (row_shr 1/2/4/8, row_bcast15/31) + readlane(63)
__device__ __forceinline__ unsigned wave_min_sgpr(unsigned v){
    unsigned t;
    t = (unsigned)__builtin_amdgcn_update_dpp((int)v,(int)v,0x111,0xF,0xF,false); v = umn(v,t);
    t = (unsigned)__builtin_amdgcn_update_dpp((int)v,(int)v,0x112,0xF,0xF,false); v = umn(v,t);
    t = (unsigned)__builtin_amdgcn_update_dpp((int)v,(int)v,0x114,0xF,0xF,false); v = umn(v,t);
    t = (unsigned)__builtin_amdgcn_update_dpp((int)v,(int)v,0x118,0xF,0xF,false); v = umn(v,t);
    t = (unsigned)__builtin_amdgcn_update_dpp((int)v,(int)v,0x142,0xF,0xF,false); v = umn(v,t);
    t = (unsigned)__builtin_amdgcn_update_dpp((int)v,(int)v,0x143,0xF,0xF,false); v = umn(v,t);
    return (unsigned)__builtin_amdgcn_readlane((int)v, 63);
}

// packed fp16 leaky-relu(0.2): lrelu(x) = max(x, 0.2x)  ->  v_pk_max_f16
__device__ __forceinline__ f16x8 lrl8(f16x8 v){
    return __builtin_elementwise_max(v, v * (_Float16)0.2f);
}

// ---------------------------------------------------------------- prep
__global__ __launch_bounds__(256) void k_prep(P p){
    int gid = blockIdx.x*256 + threadIdx.x;
    int gsz = gridDim.x*256;
    for (int i = gid; i < NB*NPT*4; i += gsz){
        int c = i & 3; int pt = i >> 2; int n = pt & (NPT-1); int b = pt >> 11;
        p.xT0[i] = (c < 3) ? p.x[((size_t)b*3 + c)*NPT + n] : 0.f;
    }
    // stage-0 split, padded to K=32: [pt][32]
    for (int i = gid; i < NB*NPT*32; i += gsz){
        int c = i & 31; int pt = i >> 5; int n = pt & (NPT-1); int b = pt >> 11;
        float xv = (c < 3) ? p.x[((size_t)b*3 + c)*NPT + n] : 0.f;
        _Float16 h = (_Float16)xv;
        p.xh0[i] = h;
        p.xl0[i] = (_Float16)(xv - (float)h);
    }
    for (int e = gid; e < 4*64; e += gsz){
        int c = e >> 6, o = e & 63;
        float a  = (c < 3) ? p.w1[o*6 + c]     : 0.f;
        float bw = (c < 3) ? p.w1[o*6 + 3 + c] : 0.f;
        p.wAT1[e] = a; p.wCT1[e] = bw - a;
    }
    #pragma unroll
    for (int k = 0; k < 3; ++k){
        const float* wsrc = (k==0) ? p.w2 : (k==1 ? p.w3 : p.w4);
        float* wa = (k==0) ? p.wAT2 : (k==1 ? p.wAT3 : p.wAT4);
        float* wc = (k==0) ? p.wCT2 : (k==1 ? p.wCT3 : p.wCT4);
        for (int e = gid; e < 64*64; e += gsz){
            int c = e >> 6, o = e & 63;
            float a = wsrc[o*128 + c];
            wa[e] = a;
            wc[e] = wsrc[o*128 + 64 + c] - a;
        }
    }
    for (int e = gid; e < 64*256; e += gsz){
        int o = e >> 8;
        float a5 = p.bn5[o] * rsqrtf(p.bn5[3*64 + o] + EPSBN);
        p.w5h[e] = (_Float16)(a5 * p.w5[e]);
    }
    for (int e = gid; e < 64*256;  e += gsz){ int c=e>>8, o=e&255; p.w6T[e]  = p.w6[o*64+c];   }
    for (int e = gid; e < 512*256; e += gsz){ int c=e>>8, o=e&255; p.lw1T[e] = p.lw1[o*512+c]; }
    for (int e = gid; e < 256*64;  e += gsz){ int c=e>>6, o=e&63;  p.lw2T[e] = p.lw2[o*256+c]; }
    auto ab = [&](const float* bn, int C, float* A, float* Bv, const float* lb){
        for (int c = gid; c < C; c += gsz){
            float s = bn[c], bb = bn[C+c], m = bn[2*C+c], v = bn[3*C+c];
            float al = s * rsqrtf(v + EPSBN);
            float be = bb - m*al;
            if (lb) be += al*lb[c];
            A[c] = al; Bv[c] = be;
        }
    };
    ab(p.bn1, 64,  p.ab+0,    p.ab+64,   nullptr);
    ab(p.bn2, 64,  p.ab+128,  p.ab+192,  nullptr);
    ab(p.bn3, 64,  p.ab+256,  p.ab+320,  nullptr);
    ab(p.bn4, 64,  p.ab+384,  p.ab+448,  nullptr);
    ab(p.bn5, 64,  p.ab+512,  p.ab+576,  nullptr);
    ab(p.bn6, 256, p.ab+640,  p.ab+896,  nullptr);
    ab(p.lbn1,256, p.ab+1152, p.ab+1408, p.lb1);
    ab(p.lbn2,64,  p.ab+1664, p.ab+1728, p.lb2);
}

// ---------------------------------------------------------------- fused kNN: two-half dist (split-fp16 MFMA) + top-20
//                                                                  + (optional) fused edge gather+maxpool
// block = 16 rows of one batch, 512 threads (8 waves). LDS = 16x1024 half-tile (65.8 KB) -> 2 blocks/CU.
// dist: wave w covers 128 cols/half; select: wave w owns rows 2w,2w+1; gather: same rows, cols from LDS.
template<int KK, bool GATHER>
__global__ __launch_bounds__(512, 4) void k_knn(const _Float16* __restrict__ xh, const _Float16* __restrict__ xl,
                                                const float* __restrict__ xx, int* __restrict__ idxo,
                                                const float* __restrict__ zA, const float* __restrict__ zC,
                                                float* __restrict__ dst){
    __shared__ float Dt[16*DHALF];
    __shared__ int colL[16][KNN];
    int w = threadIdx.x >> 6, l = threadIdx.x & 63;
    int lo = l & 15, hi = l >> 4;
    int id = blockIdx.x;
    int b = id & 7;                       // XCD batch pinning
    int n0 = (id >> 3) * 16;
    const _Float16* xhb = xh + (size_t)b*NPT*KK;
    const _Float16* xlb = xl + (size_t)b*NPT*KK;
    const float* xxb = xx + (size_t)b*NPT;
    constexpr int NF = KK/32;
    f16x8 ah[NF], al[NF];
    #pragma unroll
    for (int kk = 0; kk < NF; kk++){
        ah[kk] = *(const f16x8*)(xhb + (size_t)(n0+lo)*KK + kk*32 + hi*8);
        al[kk] = *(const f16x8*)(xlb + (size_t)(n0+lo)*KK + kk*32 + hi*8);
    }
    float xn[4];
    #pragma unroll
    for (int r = 0; r < 4; r++) xn[r] = xxb[n0 + hi*4 + r];
    unsigned key[2][32];
    #pragma unroll
    for (int half = 0; half < 2; half++){
        // ---- dist: wave w covers local cols [w*128, w*128+128) of this half
        #pragma unroll
        for (int ct = 0; ct < 8; ct++){
            int c0l = w*128 + ct*16;
            int c0 = half*1024 + c0l;
            f16x8 bh[NF], bl[NF];
            #pragma unroll
            for (int kk = 0; kk < NF; kk++){
                bh[kk] = *(const f16x8*)(xhb + (size_t)(c0+lo)*KK + kk*32 + hi*8);
                bl[kk] = *(const f16x8*)(xlb + (size_t)(c0+lo)*KK + kk*32 + hi*8);
            }
            f32x4 acc = (f32x4){0.f,0.f,0.f,0.f};
            #pragma unroll
            for (int kk = 0; kk < NF; kk++) acc = __builtin_amdgcn_mfma_f32_16x16x32_f16(ah[kk], bh[kk], acc, 0, 0, 0);
            #pragma unroll
            for (int kk = 0; kk < NF; kk++) acc = __builtin_amdgcn_mfma_f32_16x16x32_f16(ah[kk], bl[kk], acc, 0, 0, 0);
            #pragma unroll
            for (int kk = 0; kk < NF; kk++) acc = __builtin_amdgcn_mfma_f32_16x16x32_f16(al[kk], bh[kk], acc, 0, 0, 0);
            float xm = xxb[c0 + lo];
            #pragma unroll
            for (int r = 0; r < 4; r++)
                Dt[(hi*4 + r)*DHALF + c0l + lo] = xn[r] + xm - 2.f*acc[r];
        }
        __syncthreads();
        // ---- bank this half's 16 keys/lane for rows 2w, 2w+1
        #pragma unroll
        for (int rr = 0; rr < 2; rr++){
            const float* Dr = Dt + (w*2 + rr)*DHALF;
            #pragma unroll
            for (int q = 0; q < 4; q++){
                float4 v = *(const float4*)(Dr + q*256 + l*4);
                int s0 = half*16 + 4*q;
                float f0 = fmaxf(v.x,0.f), f1 = fmaxf(v.y,0.f), f2 = fmaxf(v.z,0.f), f3 = fmaxf(v.w,0.f);
                key[rr][s0+0] = (__float_as_uint(f0) & 0xFFFFFFE0u) | (unsigned)(s0+0);
                key[rr][s0+1] = (__float_as_uint(f1) & 0xFFFFFFE0u) | (unsigned)(s0+1);
                key[rr][s0+2] = (__float_as_uint(f2) & 0xFFFFFFE0u) | (unsigned)(s0+2);
                key[rr][s0+3] = (__float_as_uint(f3) & 0xFFFFFFE0u) | (unsigned)(s0+3);
            }
        }
        __syncthreads();
    }
    // ---- extraction: 2 rows interleaved (independent DPP chains)
    unsigned g[2][4];
    int* opp[2];
    #pragma unroll
    for (int rr = 0; rr < 2; rr++){
        #pragma unroll
        for (int G = 0; G < 4; G++){
            unsigned mn = key[rr][8*G];
            #pragma unroll
            for (int s = 1; s < 8; s++) mn = umn(mn, key[rr][8*G+s]);
            g[rr][G] = mn;
        }
        opp[rr] = idxo + ((size_t)b*NPT + n0 + w*2 + rr)*KNN;
    }
    for (int it = 0; it < KNN; ++it){
        unsigned lm0 = umn(umn(g[0][0],g[0][1]), umn(g[0][2],g[0][3]));
        unsigned lm1 = umn(umn(g[1][0],g[1][1]), umn(g[1][2],g[1][3]));
        unsigned wm[2];
        wm[0] = wave_min_sgpr(lm0);
        wm[1] = wave_min_sgpr(lm1);
        unsigned long long bal0 = __ballot(lm0 == wm[0]);
        unsigned long long bal1 = __ballot(lm1 == wm[1]);
        int L[2] = {__ffsll(bal0) - 1, __ffsll(bal1) - 1};
        #pragma unroll
        for (int rr = 0; rr < 2; rr++){
            int slot = (int)(wm[rr] & 31u);        // scalar
            int col = (slot>>4)*1024 + ((slot>>2)&3)*256 + L[rr]*4 + (slot&3);
            if (l == 0){
                opp[rr][it] = col;
                if (GATHER) colL[w*2 + rr][it] = col;
            }
            int Gw = slot >> 3;
            bool iwin = (l == L[rr]);
            #pragma unroll
            for (int G = 0; G < 4; G++) if (G == Gw){   // scalar branch: one group only
                unsigned mn = 0xFFFFFFFFu;
                #pragma unroll
                for (int s = 8*G; s < 8*G+8; s++){
                    unsigned kv = key[rr][s];
                    if (iwin && s == slot) kv = 0xFFFFFFFFu;
                    key[rr][s] = kv;
                    mn = umn(mn, kv);
                }
                g[rr][G] = mn;
            }
        }
    }
    // ---- fused edge gather + maxpool: y = lrelu(zA[m] + zC[pt]); dst = max_j y
    if (GATHER){
        const float* zb = zA + (size_t)b*NPT*64;
        #pragma unroll
        for (int rr = 0; rr < 2; rr++){
            int row = w*2 + rr;
            size_t ptg = (size_t)b*NPT + n0 + row;
            float zc = zC[ptg*64 + l];
            float mv = -3.4e38f;
            #pragma unroll
            for (int j = 0; j < KNN; j++){
                int m = colL[row][j];                 // LDS broadcast, wave-uniform
                float v = lrl(zb[(size_t)m*64 + l] + zc, 0.2f);
                mv = fmaxf(mv, v);
            }
            dst[ptg*64 + l] = mv;
        }
    }
}

// ---------------------------------------------------------------- per-stage projection (+xx norm, +fp16 copies, +hi/lo split)
template<int C>
__global__ __launch_bounds__(256) void k_proj(const float* __restrict__ src,
                                              const float* __restrict__ wAT, const float* __restrict__ wCT,
                                              const float* __restrict__ A, const float* __restrict__ Bv,
                                              float* __restrict__ zA, float* __restrict__ zC,
                                              _Float16* __restrict__ zAh, _Float16* __restrict__ zCh,
                                              _Float16* __restrict__ xh, _Float16* __restrict__ xl,
                                              float* __restrict__ xx){
    int wv = blockIdx.x*4 + (threadIdx.x>>6);
    int lane = threadIdx.x & 63;
    float wa[C], wc[C];
    #pragma unroll
    for (int c = 0; c < C; c++){ wa[c] = wAT[c*64+lane]; wc[c] = wCT[c*64+lane]; }
    float al = A[lane], be = Bv[lane];
    for (int p0 = 0; p0 < 4; p0++){
        int pt = wv*4 + p0;
        const float4* xr = (const float4*)(src + (size_t)pt*C);
        float sa = 0.f, sc = 0.f, sq = 0.f;
        #pragma unroll
        for (int i = 0; i < C/4; i++){
            float4 v = xr[i];
            sa += wa[4*i]*v.x + wa[4*i+1]*v.y + wa[4*i+2]*v.z + wa[4*i+3]*v.w;
            sc += wc[4*i]*v.x + wc[4*i+1]*v.y + wc[4*i+2]*v.z + wc[4*i+3]*v.w;
            sq += v.x*v.x + v.y*v.y + v.z*v.z + v.w*v.w;
        }
        float va = al*sa, vc = al*sc + be;
        zA[(size_t)pt*64 + lane] = va;
        zC[(size_t)pt*64 + lane] = vc;
        zAh[(size_t)pt*64 + lane] = (_Float16)va;
        zCh[(size_t)pt*64 + lane] = (_Float16)vc;
        if (lane == 0) xx[pt] = sq;
        if (C == 64){
            float xv = src[(size_t)pt*64 + lane];
            _Float16 h = (_Float16)xv;
            xh[(size_t)pt*64 + lane] = h;
            xl[(size_t)pt*64 + lane] = (_Float16)(xv - (float)h);
        }
    }
}

// ---------------------------------------------------------------- block5: recompute y in-register, MFMA, bn5+lrelu(max)
__global__ __launch_bounds__(256, 4) void k_block5(P p){
    __shared__ float HS[4][16*85];
    __shared__ _Float16 ZC[4][4][72];             // [stage][pt_local][64ch + pad]
    int tid = threadIdx.x;
    int wid = tid >> 6, l = tid & 63;
    int lo = l & 15, hi = l >> 4;
    int g = blockIdx.x;                           // 4096 groups of 4 points = 80 edges
    const size_t SS   = (size_t)NB*NPT*KNN;       // idx stage stride
    const size_t ZS   = (size_t)NB*NPT*64;        // zAh/zCh stage stride
    // coalesced zc staging: 4 stages x 4 pts x 64 halves = 1024 halves; 4 per thread
    {
        int q = tid * 4;
        int s = q >> 8, ptl = (q >> 6) & 3, c = q & 63;
        int pt = g*4 + ptl;
        *(f16x4*)&ZC[s][ptl][c] = *(const f16x4*)(p.zCh + (size_t)s*ZS + (size_t)pt*64 + c);
    }
    __syncthreads();
    f16x8 af[8];
    #pragma unroll
    for (int kk = 0; kk < 8; kk++)
        af[kk] = *(const f16x8*)(p.w5h + (wid*16 + lo)*256 + kk*32 + hi*8);
    // prefetch all 20 neighbor indices (breaks idx->gather serial chain)
    int mm[5][4];
    #pragma unroll
    for (int et = 0; et < 5; et++){
        int e = g*80 + et*16 + lo;
        #pragma unroll
        for (int s = 0; s < 4; s++) mm[et][s] = p.idx[(size_t)s*SS + e];
    }
    f32x4 acc[5];
    #pragma unroll
    for (int et = 0; et < 5; et++) acc[et] = (f32x4){0.f,0.f,0.f,0.f};
    #pragma unroll
    for (int et = 0; et < 5; et++){
        int e  = g*80 + et*16 + lo;
        int pt = e / 20;
        int b  = pt >> 11;
        int ptl = pt & 3;
        #pragma unroll
        for (int s = 0; s < 4; s++){
            int m = mm[et][s];
            const f16x8* za  = (const f16x8*)(p.zAh + (size_t)s*ZS + ((size_t)(b*NPT + m))*64 + hi*8);
            const f16x8* zcl = (const f16x8*)&ZC[s][ptl][hi*8];
            f16x8 y0 = lrl8(za[0] + zcl[0]);
            f16x8 y1 = lrl8(za[4] + zcl[4]);
            acc[et] = __builtin_amdgcn_mfma_f32_16x16x32_f16(af[2*s+0], y0, acc[et], 0, 0, 0);
            acc[et] = __builtin_amdgcn_mfma_f32_16x16x32_f16(af[2*s+1], y1, acc[et], 0, 0, 0);
        }
    }
    float* Hw = HS[wid];
    #pragma unroll
    for (int et = 0; et < 5; et++){
        #pragma unroll
        for (int r = 0; r < 4; r++)
            Hw[(hi*4 + r)*85 + et*16 + lo] = acc[et][r];
    }
    float mv = -3.4e38f;
    #pragma unroll
    for (int j = 0; j < KNN; j++)
        mv = fmaxf(mv, Hw[lo*85 + hi*20 + j]);
    int o = wid*16 + lo;
    int pt = g*4 + hi;
    float b5 = p.ab[576+o];
    p.h5T[(size_t)pt*64 + o] = lrl(mv + b5, 0.2f);
}

// ---------------------------------------------------------------- block6 conv + partial pools
__global__ __launch_bounds__(256) void k_block6(P p){
    int o = threadIdx.x;
    int ch = blockIdx.x, b = blockIdx.y;
    float w6r[64];
    #pragma unroll
    for (int c = 0; c < 64; c++) w6r[c] = p.w6T[c*256 + o];
    float a6 = p.ab[640+o], b6 = p.ab[896+o];
    float mv = -3.4e38f, sm = 0.f;
    for (int n = ch*128; n < ch*128 + 128; ++n){
        const float4* h4 = (const float4*)(p.h5T + ((size_t)b*NPT + n)*64);
        float t = 0.f;
        #pragma unroll
        for (int i = 0; i < 16; i++){
            float4 v = h4[i];
            t += w6r[4*i]*v.x + w6r[4*i+1]*v.y + w6r[4*i+2]*v.z + w6r[4*i+3]*v.w;
        }
        float y = lrl(a6*t + b6, 0.2f);
        mv = fmaxf(mv, y); sm += y;
    }
    p.pmax[((size_t)b*16 + ch)*256 + o] = mv;
    p.psum[((size_t)b*16 + ch)*256 + o] = sm;
}

// ---------------------------------------------------------------- final pool + FC head
__global__ __launch_bounds__(256) void k_head(P p){
    __shared__ float g[512], z1[256], z2[64];
    int b = blockIdx.x, o = threadIdx.x;
    float mv = -3.4e38f, sm = 0.f;
    for (int ch = 0; ch < 16; ++ch){
        mv = fmaxf(mv, p.pmax[((size_t)b*16+ch)*256 + o]);
        sm += p.psum[((size_t)b*16+ch)*256 + o];
    }
    g[o] = mv; g[256+o] = sm * (1.f/NPT);
    __syncthreads();
    float t = 0.f;
    for (int c = 0; c < 512; c++) t += g[c]*p.lw1T[c*256 + o];
    z1[o] = lrl(p.ab[1152+o]*t + p.ab[1408+o], 0.01f);
    __syncthreads();
    if (o < 64){
        float t2 = 0.f;
        for (int c = 0; c < 256; c++) t2 += z1[c]*p.lw2T[c*64 + o];
        z2[o] = lrl(p.ab[1664+o]*t2 + p.ab[1728+o], 0.01f);
    }
    __syncthreads();
    if (o < CLS){
        float t3 = p.lb3[o];
        for (int c = 0; c < 64; c++) t3 += z2[c]*p.lw3[o*64 + c];
        p.out[(size_t)b*CLS + o] = t3;
    }
}

// ---------------------------------------------------------------- host
extern "C" void kernel_launch(void* const* d_in, const int* in_sizes, int n_in,
                              void* d_out, int out_size, void* d_ws, size_t ws_size,
                              hipStream_t stream){
    P p;
    p.x   = (const float*)d_in[0];
    p.w1  = (const float*)d_in[1];  p.bn1 = (const float*)d_in[2];
    p.w2  = (const float*)d_in[3];  p.bn2 = (const float*)d_in[4];
    p.w3  = (const float*)d_in[5];  p.bn3 = (const float*)d_in[6];
    p.w4  = (const float*)d_in[7];  p.bn4 = (const float*)d_in[8];
    p.w5  = (const float*)d_in[9];  p.bn5 = (const float*)d_in[10];
    p.w6  = (const float*)d_in[11]; p.bn6 = (const float*)d_in[12];
    p.lw1 = (const float*)d_in[13]; p.lb1 = (const float*)d_in[14]; p.lbn1 = (const float*)d_in[15];
    p.lw2 = (const float*)d_in[16]; p.lb2 = (const float*)d_in[17]; p.lbn2 = (const float*)d_in[18];
    p.lw3 = (const float*)d_in[19]; p.lb3 = (const float*)d_in[20];
    p.out = (float*)d_out;

    float* w = (float*)d_ws;
    size_t off = 0;
    auto alloc = [&](size_t n)->float*{ float* r = w + off; off += (n + 63) & ~(size_t)63; return r; };
    p.xT0  = alloc((size_t)NB*NPT*4);
    p.xT1  = alloc((size_t)NB*NPT*64);
    p.xT2  = alloc((size_t)NB*NPT*64);
    p.xT3  = alloc((size_t)NB*NPT*64);
    p.h5T  = alloc((size_t)NB*NPT*64);
    p.xx   = alloc((size_t)NB*NPT);
    p.idx  = (int*)alloc((size_t)4*NB*NPT*KNN);
    p.wAT1 = alloc(256);  p.wCT1 = alloc(256);
    p.wAT2 = alloc(4096); p.wCT2 = alloc(4096);
    p.wAT3 = alloc(4096); p.wCT3 = alloc(4096);
    p.wAT4 = alloc(4096); p.wCT4 = alloc(4096);
    p.ab   = alloc(1792);
    p.zA   = alloc((size_t)NB*NPT*64);
    p.zC   = alloc((size_t)NB*NPT*64);
    const size_t ZS = (size_t)NB*NPT*64;              // fp16 elements per stage
    p.zAh = (_Float16*)alloc(4*ZS/2);
    p.zCh = (_Float16*)alloc(4*ZS/2);
    p.xh  = (_Float16*)alloc(ZS/2);
    p.xl  = (_Float16*)alloc(ZS/2);
    p.xh0 = (_Float16*)alloc((size_t)NB*NPT*32/2);
    p.xl0 = (_Float16*)alloc((size_t)NB*NPT*32/2);
    p.w5h = (_Float16*)alloc(64*256/2);
    p.w6T  = alloc(16384);
    p.lw1T = alloc(131072); p.lw2T = alloc(16384);
    p.pmax = alloc((size_t)NB*16*256);
    p.psum = alloc((size_t)NB*16*256);

    k_prep<<<64, 256, 0, stream>>>(p);
    const size_t SS = (size_t)NB*NPT*KNN;
    for (int s = 0; s < 4; s++){
        const float* src = (s==0) ? p.xT0 : (s==1 ? p.xT1 : (s==2 ? p.xT2 : p.xT3));
        float* dst = (s==0) ? p.xT1 : (s==1 ? p.xT2 : p.xT3);
        int* idxs = p.idx + (size_t)s*SS;
        _Float16* zAh = p.zAh + (size_t)s*ZS;
        _Float16* zCh = p.zCh + (size_t)s*ZS;
        if (s == 0)      k_proj<4 ><<<NB*NPT/16, 256, 0, stream>>>(src, p.wAT1, p.wCT1, p.ab+0,   p.ab+64,  p.zA, p.zC, zAh, zCh, p.xh, p.xl, p.xx);
        else if (s == 1) k_proj<64><<<NB*NPT/16, 256, 0, stream>>>(src, p.wAT2, p.wCT2, p.ab+128, p.ab+192, p.zA, p.zC, zAh, zCh, p.xh, p.xl, p.xx);
        else if (s == 2) k_proj<64><<<NB*NPT/16, 256, 0, stream>>>(src, p.wAT3, p.wCT3, p.ab+256, p.ab+320, p.zA, p.zC, zAh, zCh, p.xh, p.xl, p.xx);
        else             k_proj<64><<<NB*NPT/16, 256, 0, stream>>>(src, p.wAT4, p.wCT4, p.ab+384, p.ab+448, p.zA, p.zC, zAh, zCh, p.xh, p.xl, p.xx);
        if (s == 0)      k_knn<32,true ><<<NB*NPT/16, 512, 0, stream>>>(p.xh0, p.xl0, p.xx, idxs, p.zA, p.zC, dst);
        else if (s == 3) k_knn<64,false><<<NB*NPT/16, 512, 0, stream>>>(p.xh,  p.xl,  p.xx, idxs, p.zA, p.zC, nullptr);
        else             k_knn<64,true ><<<NB*NPT/16, 512, 0, stream>>>(p.xh,  p.xl,  p.xx, idxs, p.zA, p.zC, dst);
        // s==3: x4 unused -> no gather; only idx4 + zAh4/zCh4 needed by block5
    }
    k_block5<<<NB*NPT/4, 256, 0, stream>>>(p);
    k_block6<<<dim3(16, NB), 256, 0, stream>>>(p);
    k_head<<<NB, 256, 0, stream>>>(p);
}